// Round 1
// baseline (4986.058 us; speedup 1.0000x reference)
//
#include <hip/hip_runtime.h>
#include <cstddef>
#include <cstdint>

#define NB   8
#define LQ   1024
#define CH   512
#define HHE  8
#define HDD  64
#define PPM  16
#define LP   1040     // L + P
#define HID  2048

// ---- workspace layout (floats) ----
static const size_t OFF_R0 = 0;          // q -> ao -> f            (4,194,304)
static const size_t OFF_R1 = 4194304;    // k ; later w1pack (6,291,456 spans R1+R2 head)
static const size_t OFF_R2 = 8454144;    // v ; later a (attn+res)  (4,259,840)
static const size_t OFF_R3 = 12713984;   // h                       (16,777,216)
static const size_t OFF_W2 = 29491200;   // w2pack                  (3,145,728)
static const size_t OFF_WO = 32636928;   // WoT pack                (262,144)
// total = 32,899,072 floats = 131.6 MB

// ---------------------------------------------------------------------------
// pack: dst[(dl*IC+ic)*OC + oc] = src[oc*ICKD + ic*KD + dl]
// grid: (K/64, OC/64), 256 threads
// ---------------------------------------------------------------------------
__global__ __launch_bounds__(256) void pack_w_kernel(
    const float* __restrict__ src, float* __restrict__ dst,
    int OC, int ICKD, int KD, int icShift)
{
  __shared__ float tile[64][65];
  const int k0  = blockIdx.x * 64;
  const int oc0 = blockIdx.y * 64;
  const int t = threadIdx.x;
  const int lane = t & 63, quad = t >> 6;
  const int icMask = (1 << icShift) - 1;
  const int k = k0 + lane;
  const int ic = k & icMask, dl = k >> icShift;
  for (int j = 0; j < 16; ++j) {
    int oc_l = quad * 16 + j;
    tile[oc_l][lane] = src[(size_t)(oc0 + oc_l) * ICKD + ic * KD + dl];
  }
  __syncthreads();
  for (int j = 0; j < 16; ++j) {
    int kk = quad * 16 + j;
    dst[(size_t)(k0 + kk) * OC + oc0 + lane] = tile[lane][kk];
  }
}

// ---------------------------------------------------------------------------
// QKV projection: per token, q/k/v[h,d] = sum_e W[d,e] * x[h,e]
// grid: 8192 blocks (one per token), 256 threads
// ---------------------------------------------------------------------------
__global__ __launch_bounds__(256) void qkv_kernel(
    const float* __restrict__ x,
    const float* __restrict__ Wq, const float* __restrict__ Wk, const float* __restrict__ Wv,
    float* __restrict__ qo, float* __restrict__ ko, float* __restrict__ vo)
{
  __shared__ float xr[512];
  const int tok = blockIdx.x;
  const int n = tok >> 10, l = tok & 1023;
  const int t = threadIdx.x;
  ((float2*)xr)[t] = ((const float2*)(x + (size_t)tok * CH))[t];
  __syncthreads();
  const size_t qbase  = (size_t)tok * CH;
  const size_t kvbase = ((size_t)n * LP + l) * CH;
  #pragma unroll
  for (int half = 0; half < 2; ++half) {
    const int o = t + half * 256;
    const int h = o >> 6, d = o & 63;
    const float* xs = xr + h * 64;
    const float4* wq4 = (const float4*)(Wq + d * 64);
    const float4* wk4 = (const float4*)(Wk + d * 64);
    const float4* wv4 = (const float4*)(Wv + d * 64);
    float sq = 0.f, sk = 0.f, sv = 0.f;
    #pragma unroll
    for (int c = 0; c < 16; ++c) {
      float4 aq = wq4[c], ak = wk4[c], av = wv4[c];
      float x0 = xs[c*4+0], x1 = xs[c*4+1], x2 = xs[c*4+2], x3 = xs[c*4+3];
      sq += aq.x*x0 + aq.y*x1 + aq.z*x2 + aq.w*x3;
      sk += ak.x*x0 + ak.y*x1 + ak.z*x2 + ak.w*x3;
      sv += av.x*x0 + av.y*x1 + av.z*x2 + av.w*x3;
    }
    qo[qbase + o]  = sq;
    ko[kvbase + o] = sk;
    vo[kvbase + o] = sv;
  }
}

// persistent memory rows: k/v[n, L+p, h, d] = p_*[p, 0, d]
__global__ __launch_bounds__(256) void persist_kernel(
    const float* __restrict__ pk, const float* __restrict__ pv,
    float* __restrict__ ko, float* __restrict__ vo)
{
  const int t = blockIdx.x * 256 + threadIdx.x;   // < 8*16*512
  const int n = t >> 13, p = (t >> 9) & 15, c = t & 511, d = c & 63;
  const size_t o = ((size_t)n * LP + LQ + p) * CH + c;
  ko[o] = pk[p * 64 + d];
  vo[o] = pv[p * 64 + d];
}

// ---------------------------------------------------------------------------
// Fused attention: ALiBi + th_pre + softmax + th_post + AV.
// Two-pass online softmax (energy recomputed in pass 2).
// grid: (L/16, N), 256 threads. Writes ao (aliases q buffer: block reads its
// own q rows before writing its own ao rows).
// ---------------------------------------------------------------------------
__global__ __launch_bounds__(256, 2) void attn_kernel(
    const float* q, const float* __restrict__ kb, const float* __restrict__ vb,
    const float* __restrict__ thpre, const float* __restrict__ thpost,
    float* ao)
{
  __shared__ float qs[16][516];
  __shared__ float ks[16][516];
  __shared__ float at2[16][8][17];
  __shared__ float tpre[64], tpost[64];
  const int n  = blockIdx.y;
  const int q0 = blockIdx.x * 16;
  const int t  = threadIdx.x;

  #pragma unroll
  for (int j = 0; j < 8; ++j) {
    int f = t + 256 * j, r = f >> 7, c4 = f & 127;
    *(float4*)&qs[r][c4 << 2] =
        *(const float4*)&q[((size_t)(n * LQ + q0 + r)) * CH + (c4 << 2)];
  }
  if (t < 64) { tpre[t] = thpre[t]; tpost[t] = thpost[t]; }
  __syncthreads();

  const int tq = t >> 4, l16 = t & 15;
  const int qidx = q0 + tq;
  const float invs = 0.044194173824159216f;  // 1/sqrt(512)
  const float slope[8] = {0.5f, 0.25f, 0.125f, 0.0625f,
                          0.03125f, 0.015625f, 0.0078125f, 0.00390625f};
  float mrun[8], zrun[8];
  #pragma unroll
  for (int g = 0; g < 8; ++g) { mrun[g] = -1e30f; zrun[g] = 0.f; }

  // ---------------- pass 1: running (m, z) ----------------
  for (int kt = 0; kt < 65; ++kt) {
    const int k0 = kt * 16;
    __syncthreads();
    #pragma unroll
    for (int j = 0; j < 8; ++j) {
      int f = t + 256 * j, r = f >> 7, c4 = f & 127;
      *(float4*)&ks[r][c4 << 2] =
          *(const float4*)&kb[((size_t)(n * LP + k0 + r)) * CH + (c4 << 2)];
    }
    __syncthreads();
    float e[8];
    #pragma unroll
    for (int h = 0; h < 8; ++h) e[h] = 0.f;
    const float4* kr = (const float4*)&ks[l16][0];
    const float4* qr = (const float4*)&qs[tq][0];
    for (int c = 0; c < 16; ++c) {
      #pragma unroll
      for (int h = 0; h < 8; ++h) {
        float4 kv = kr[h * 16 + c], qv = qr[h * 16 + c];
        e[h] += kv.x*qv.x + kv.y*qv.y + kv.z*qv.z + kv.w*qv.w;
      }
    }
    const int kk = k0 + l16;
    if (kk < LQ) {
      float dist = fabsf((float)(qidx - kk));
      #pragma unroll
      for (int h = 0; h < 8; ++h) e[h] -= dist * slope[h];
    }
    #pragma unroll
    for (int g = 0; g < 8; ++g) {
      float s = 0.f;
      #pragma unroll
      for (int h = 0; h < 8; ++h) s += tpre[g * 8 + h] * e[h];
      s *= invs;
      float nm = fmaxf(mrun[g], s);
      zrun[g] = zrun[g] * __expf(mrun[g] - nm) + __expf(s - nm);
      mrun[g] = nm;
    }
  }
  // combine (m,z) across the 16 lanes sharing tq
  #pragma unroll
  for (int off = 1; off < 16; off <<= 1) {
    #pragma unroll
    for (int g = 0; g < 8; ++g) {
      float mo = __shfl_xor(mrun[g], off);
      float zo = __shfl_xor(zrun[g], off);
      float nm = fmaxf(mrun[g], mo);
      zrun[g] = zrun[g] * __expf(mrun[g] - nm) + zo * __expf(mo - nm);
      mrun[g] = nm;
    }
  }
  float zi[8];
  #pragma unroll
  for (int g = 0; g < 8; ++g) zi[g] = 1.0f / zrun[g];

  // ---------------- pass 2: attn2 tile + AV ----------------
  float acc[16][2];
  #pragma unroll
  for (int r = 0; r < 16; ++r) { acc[r][0] = 0.f; acc[r][1] = 0.f; }
  const int g2 = t >> 5;
  const int o2 = t << 1;

  for (int kt = 0; kt < 65; ++kt) {
    const int k0 = kt * 16;
    __syncthreads();
    #pragma unroll
    for (int j = 0; j < 8; ++j) {
      int f = t + 256 * j, r = f >> 7, c4 = f & 127;
      *(float4*)&ks[r][c4 << 2] =
          *(const float4*)&kb[((size_t)(n * LP + k0 + r)) * CH + (c4 << 2)];
    }
    __syncthreads();
    float e[8];
    #pragma unroll
    for (int h = 0; h < 8; ++h) e[h] = 0.f;
    const float4* kr = (const float4*)&ks[l16][0];
    const float4* qr = (const float4*)&qs[tq][0];
    for (int c = 0; c < 16; ++c) {
      #pragma unroll
      for (int h = 0; h < 8; ++h) {
        float4 kv = kr[h * 16 + c], qv = qr[h * 16 + c];
        e[h] += kv.x*qv.x + kv.y*qv.y + kv.z*qv.z + kv.w*qv.w;
      }
    }
    const int kk = k0 + l16;
    if (kk < LQ) {
      float dist = fabsf((float)(qidx - kk));
      #pragma unroll
      for (int h = 0; h < 8; ++h) e[h] -= dist * slope[h];
    }
    float p[8];
    #pragma unroll
    for (int g = 0; g < 8; ++g) {
      float s = 0.f;
      #pragma unroll
      for (int h = 0; h < 8; ++h) s += tpre[g * 8 + h] * e[h];
      s *= invs;
      p[g] = __expf(s - mrun[g]) * zi[g];
    }
    #pragma unroll
    for (int gg = 0; gg < 8; ++gg) {
      float a = 0.f;
      #pragma unroll
      for (int g = 0; g < 8; ++g) a += tpost[gg * 8 + g] * p[g];
      at2[tq][gg][l16] = a;
    }
    __syncthreads();
    for (int kk2 = 0; kk2 < 16; ++kk2) {
      float2 v2 = *(const float2*)&vb[((size_t)(n * LP + k0 + kk2)) * CH + o2];
      #pragma unroll
      for (int r = 0; r < 16; ++r) {
        float w = at2[r][g2][kk2];
        acc[r][0] += w * v2.x;
        acc[r][1] += w * v2.y;
      }
    }
  }
  #pragma unroll
  for (int r = 0; r < 16; ++r) {
    float2 o; o.x = acc[r][0]; o.y = acc[r][1];
    *(float2*)&ao[((size_t)(n * LQ + q0 + r)) * CH + o2] = o;
  }
}

// ---------------------------------------------------------------------------
// Wo GEMM + bias + residual:  a = ao @ Wo^T + bo + x
// grid (128, 8), 256 threads, 64x64 tile, 4x4/thread
// ---------------------------------------------------------------------------
__global__ __launch_bounds__(256, 2) void wo_kernel(
    const float* __restrict__ A, const float* __restrict__ Bp,
    const float* __restrict__ bo, const float* __restrict__ x,
    float* __restrict__ outp)
{
  __shared__ float As[32][65];
  __shared__ float Bs[32][68];
  const int tok0 = blockIdx.x * 64;
  const int oc0  = blockIdx.y * 64;
  const int t = threadIdx.x, tx = t & 15, ty = t >> 4;
  float acc[4][4] = {};
  for (int kt = 0; kt < 16; ++kt) {
    const int k0 = kt * 32;
    __syncthreads();
    #pragma unroll
    for (int j = 0; j < 8; ++j) {
      int f = t + 256 * j, col = f & 31, row = f >> 5;
      As[col][row] = A[(size_t)(tok0 + row) * CH + k0 + col];
    }
    #pragma unroll
    for (int j = 0; j < 8; ++j) {
      int f = t + 256 * j, oc = f & 63, kk = f >> 6;
      Bs[kk][oc] = Bp[(size_t)(k0 + kk) * CH + oc0 + oc];
    }
    __syncthreads();
    #pragma unroll 8
    for (int kk = 0; kk < 32; ++kk) {
      float4 a4 = *(const float4*)&As[kk][ty << 2];
      float4 b4 = *(const float4*)&Bs[kk][tx << 2];
      acc[0][0] += a4.x*b4.x; acc[0][1] += a4.x*b4.y; acc[0][2] += a4.x*b4.z; acc[0][3] += a4.x*b4.w;
      acc[1][0] += a4.y*b4.x; acc[1][1] += a4.y*b4.y; acc[1][2] += a4.y*b4.z; acc[1][3] += a4.y*b4.w;
      acc[2][0] += a4.z*b4.x; acc[2][1] += a4.z*b4.y; acc[2][2] += a4.z*b4.z; acc[2][3] += a4.z*b4.w;
      acc[3][0] += a4.w*b4.x; acc[3][1] += a4.w*b4.y; acc[3][2] += a4.w*b4.z; acc[3][3] += a4.w*b4.w;
    }
  }
  float4 bv = *(const float4*)&bo[oc0 + (tx << 2)];
  #pragma unroll
  for (int i = 0; i < 4; ++i) {
    int row = tok0 + (ty << 2) + i;
    float4 xv = *(const float4*)&x[(size_t)row * CH + oc0 + (tx << 2)];
    float4 o;
    o.x = acc[i][0] + bv.x + xv.x;
    o.y = acc[i][1] + bv.y + xv.y;
    o.z = acc[i][2] + bv.z + xv.z;
    o.w = acc[i][3] + bv.w + xv.w;
    *(float4*)&outp[(size_t)row * CH + oc0 + (tx << 2)] = o;
  }
}

// ---------------------------------------------------------------------------
// conv1 (k=3, C->4096) + swiglu.  grid (128, 32).
// block computes cols [oc0,oc0+64) and [oc0+2048,+64), K = 1536
// ---------------------------------------------------------------------------
__global__ __launch_bounds__(256, 2) void conv1_kernel(
    const float* __restrict__ x1, const float* __restrict__ Bp,
    const float* __restrict__ bias, float* __restrict__ hbuf)
{
  __shared__ float As[32][65];
  __shared__ float Bs1[32][68];
  __shared__ float Bs2[32][68];
  const int tok0 = blockIdx.x * 64;
  const int oc0  = blockIdx.y * 64;
  const int t = threadIdx.x, tx = t & 15, ty = t >> 4;
  const int n = tok0 >> 10, l0 = tok0 & 1023;
  float acc1[4][4] = {};
  float acc2[4][4] = {};
  for (int kt = 0; kt < 48; ++kt) {
    const int k0 = kt * 32;
    const int dl = k0 >> 9;
    const int ic0 = k0 & 511;
    __syncthreads();
    #pragma unroll
    for (int j = 0; j < 8; ++j) {
      int f = t + 256 * j, col = f & 31, row = f >> 5;
      int lp = l0 + row + dl - 1;
      float v = 0.f;
      if (lp >= 0 && lp < LQ)
        v = x1[((size_t)(n << 10) + lp) * CH + ic0 + col];
      As[col][row] = v;
    }
    #pragma unroll
    for (int j = 0; j < 8; ++j) {
      int f = t + 256 * j, oc = f & 63, kk = f >> 6;
      size_t base = (size_t)(k0 + kk) * 4096;
      Bs1[kk][oc] = Bp[base + oc0 + oc];
      Bs2[kk][oc] = Bp[base + 2048 + oc0 + oc];
    }
    __syncthreads();
    #pragma unroll 8
    for (int kk = 0; kk < 32; ++kk) {
      float4 a4 = *(const float4*)&As[kk][ty << 2];
      float4 b4 = *(const float4*)&Bs1[kk][tx << 2];
      float4 c4 = *(const float4*)&Bs2[kk][tx << 2];
      acc1[0][0] += a4.x*b4.x; acc1[0][1] += a4.x*b4.y; acc1[0][2] += a4.x*b4.z; acc1[0][3] += a4.x*b4.w;
      acc1[1][0] += a4.y*b4.x; acc1[1][1] += a4.y*b4.y; acc1[1][2] += a4.y*b4.z; acc1[1][3] += a4.y*b4.w;
      acc1[2][0] += a4.z*b4.x; acc1[2][1] += a4.z*b4.y; acc1[2][2] += a4.z*b4.z; acc1[2][3] += a4.z*b4.w;
      acc1[3][0] += a4.w*b4.x; acc1[3][1] += a4.w*b4.y; acc1[3][2] += a4.w*b4.z; acc1[3][3] += a4.w*b4.w;
      acc2[0][0] += a4.x*c4.x; acc2[0][1] += a4.x*c4.y; acc2[0][2] += a4.x*c4.z; acc2[0][3] += a4.x*c4.w;
      acc2[1][0] += a4.y*c4.x; acc2[1][1] += a4.y*c4.y; acc2[1][2] += a4.y*c4.z; acc2[1][3] += a4.y*c4.w;
      acc2[2][0] += a4.z*c4.x; acc2[2][1] += a4.z*c4.y; acc2[2][2] += a4.z*c4.z; acc2[2][3] += a4.z*c4.w;
      acc2[3][0] += a4.w*c4.x; acc2[3][1] += a4.w*c4.y; acc2[3][2] += a4.w*c4.z; acc2[3][3] += a4.w*c4.w;
    }
  }
  float4 b1v = *(const float4*)&bias[oc0 + (tx << 2)];
  float4 b2v = *(const float4*)&bias[2048 + oc0 + (tx << 2)];
  #pragma unroll
  for (int i = 0; i < 4; ++i) {
    int row = tok0 + (ty << 2) + i;
    float4 o;
    {
      float v1 = acc1[i][0] + b1v.x, v2 = acc2[i][0] + b2v.x;
      o.x = (v1 / (1.f + __expf(-v1))) * v2;
      v1 = acc1[i][1] + b1v.y; v2 = acc2[i][1] + b2v.y;
      o.y = (v1 / (1.f + __expf(-v1))) * v2;
      v1 = acc1[i][2] + b1v.z; v2 = acc2[i][2] + b2v.z;
      o.z = (v1 / (1.f + __expf(-v1))) * v2;
      v1 = acc1[i][3] + b1v.w; v2 = acc2[i][3] + b2v.w;
      o.w = (v1 / (1.f + __expf(-v1))) * v2;
    }
    *(float4*)&hbuf[(size_t)row * HID + oc0 + (tx << 2)] = o;
  }
}

// ---------------------------------------------------------------------------
// conv2 (k=3, 2048->512) + bias.  grid (128, 8), K = 6144
// ---------------------------------------------------------------------------
__global__ __launch_bounds__(256, 2) void conv2_kernel(
    const float* __restrict__ hbuf, const float* __restrict__ Bp,
    const float* __restrict__ bias, float* __restrict__ fbuf)
{
  __shared__ float As[32][65];
  __shared__ float Bs[32][68];
  const int tok0 = blockIdx.x * 64;
  const int oc0  = blockIdx.y * 64;
  const int t = threadIdx.x, tx = t & 15, ty = t >> 4;
  const int n = tok0 >> 10, l0 = tok0 & 1023;
  float acc[4][4] = {};
  for (int kt = 0; kt < 192; ++kt) {
    const int k0 = kt * 32;
    const int dl = k0 >> 11;
    const int ic0 = k0 & 2047;
    __syncthreads();
    #pragma unroll
    for (int j = 0; j < 8; ++j) {
      int f = t + 256 * j, col = f & 31, row = f >> 5;
      int lp = l0 + row + dl - 1;
      float v = 0.f;
      if (lp >= 0 && lp < LQ)
        v = hbuf[((size_t)(n << 10) + lp) * HID + ic0 + col];
      As[col][row] = v;
    }
    #pragma unroll
    for (int j = 0; j < 8; ++j) {
      int f = t + 256 * j, oc = f & 63, kk = f >> 6;
      Bs[kk][oc] = Bp[(size_t)(k0 + kk) * CH + oc0 + oc];
    }
    __syncthreads();
    #pragma unroll 8
    for (int kk = 0; kk < 32; ++kk) {
      float4 a4 = *(const float4*)&As[kk][ty << 2];
      float4 b4 = *(const float4*)&Bs[kk][tx << 2];
      acc[0][0] += a4.x*b4.x; acc[0][1] += a4.x*b4.y; acc[0][2] += a4.x*b4.z; acc[0][3] += a4.x*b4.w;
      acc[1][0] += a4.y*b4.x; acc[1][1] += a4.y*b4.y; acc[1][2] += a4.y*b4.z; acc[1][3] += a4.y*b4.w;
      acc[2][0] += a4.z*b4.x; acc[2][1] += a4.z*b4.y; acc[2][2] += a4.z*b4.z; acc[2][3] += a4.z*b4.w;
      acc[3][0] += a4.w*b4.x; acc[3][1] += a4.w*b4.y; acc[3][2] += a4.w*b4.z; acc[3][3] += a4.w*b4.w;
    }
  }
  float4 bv = *(const float4*)&bias[oc0 + (tx << 2)];
  #pragma unroll
  for (int i = 0; i < 4; ++i) {
    int row = tok0 + (ty << 2) + i;
    float4 o;
    o.x = acc[i][0] + bv.x;
    o.y = acc[i][1] + bv.y;
    o.z = acc[i][2] + bv.z;
    o.w = acc[i][3] + bv.w;
    *(float4*)&fbuf[(size_t)row * CH + oc0 + (tx << 2)] = o;
  }
}

// ---------------------------------------------------------------------------
// LayerNorm over last dim (512). One wave per token, 4 tokens/block.
// If res != nullptr: input = in + res (elementwise) before LN.
// grid 2048, 256 threads.
// ---------------------------------------------------------------------------
__global__ __launch_bounds__(256) void ln_kernel(
    const float* in, const float* res,
    const float* g, const float* b, float* outp)
{
  const int w = threadIdx.x >> 6, lane = threadIdx.x & 63;
  const int tok = blockIdx.x * 4 + w;
  const size_t base = (size_t)tok * CH;
  float4 v0 = *(const float4*)&in[base + (lane << 2)];
  float4 v1 = *(const float4*)&in[base + 256 + (lane << 2)];
  if (res != nullptr) {
    float4 r0 = *(const float4*)&res[base + (lane << 2)];
    float4 r1 = *(const float4*)&res[base + 256 + (lane << 2)];
    v0.x += r0.x; v0.y += r0.y; v0.z += r0.z; v0.w += r0.w;
    v1.x += r1.x; v1.y += r1.y; v1.z += r1.z; v1.w += r1.w;
  }
  float s = v0.x + v0.y + v0.z + v0.w + v1.x + v1.y + v1.z + v1.w;
  #pragma unroll
  for (int off = 32; off > 0; off >>= 1) s += __shfl_xor(s, off);
  const float mu = s * (1.f / 512.f);
  float d0 = v0.x - mu, d1 = v0.y - mu, d2 = v0.z - mu, d3 = v0.w - mu;
  float d4 = v1.x - mu, d5 = v1.y - mu, d6 = v1.z - mu, d7 = v1.w - mu;
  float vs = d0*d0 + d1*d1 + d2*d2 + d3*d3 + d4*d4 + d5*d5 + d6*d6 + d7*d7;
  #pragma unroll
  for (int off = 32; off > 0; off >>= 1) vs += __shfl_xor(vs, off);
  const float r = rsqrtf(vs * (1.f / 512.f) + 1e-5f);
  float4 ga = *(const float4*)&g[(lane << 2)];
  float4 gb = *(const float4*)&g[256 + (lane << 2)];
  float4 ba = *(const float4*)&b[(lane << 2)];
  float4 bb = *(const float4*)&b[256 + (lane << 2)];
  float4 o0, o1;
  o0.x = d0 * r * ga.x + ba.x; o0.y = d1 * r * ga.y + ba.y;
  o0.z = d2 * r * ga.z + ba.z; o0.w = d3 * r * ga.w + ba.w;
  o1.x = d4 * r * gb.x + bb.x; o1.y = d5 * r * gb.y + bb.y;
  o1.z = d6 * r * gb.z + bb.z; o1.w = d7 * r * gb.w + bb.w;
  *(float4*)&outp[base + (lane << 2)] = o0;
  *(float4*)&outp[base + 256 + (lane << 2)] = o1;
}

// ---------------------------------------------------------------------------
extern "C" void kernel_launch(void* const* d_in, const int* in_sizes, int n_in,
                              void* d_out, int out_size, void* d_ws, size_t ws_size,
                              hipStream_t stream)
{
  (void)in_sizes; (void)n_in; (void)out_size; (void)ws_size;
  const float* x      = (const float*)d_in[0];
  const float* Wq     = (const float*)d_in[1];
  const float* Wk     = (const float*)d_in[2];
  const float* Wv     = (const float*)d_in[3];
  const float* Wo     = (const float*)d_in[4];
  const float* bo     = (const float*)d_in[5];
  const float* th_pre = (const float*)d_in[6];
  const float* th_post= (const float*)d_in[7];
  const float* p_keys = (const float*)d_in[8];
  const float* p_vals = (const float*)d_in[9];
  const float* c1w    = (const float*)d_in[10];
  const float* c1b    = (const float*)d_in[11];
  const float* c2w    = (const float*)d_in[12];
  const float* c2b    = (const float*)d_in[13];
  const float* ln1g   = (const float*)d_in[14];
  const float* ln1b   = (const float*)d_in[15];
  const float* ln2g   = (const float*)d_in[16];
  const float* ln2b   = (const float*)d_in[17];

  float* ws  = (float*)d_ws;
  float* out = (float*)d_out;

  float* qbf = ws + OFF_R0;   // q, then ao (safe alias), then f
  float* kbf = ws + OFF_R1;
  float* vbf = ws + OFF_R2;
  float* abf = ws + OFF_R2;   // Wo output (v dead by then)
  float* w1p = ws + OFF_R1;   // packed conv1 weights (k/v dead after LN1)
  float* hbf = ws + OFF_R3;
  float* w2p = ws + OFF_W2;
  float* wop = ws + OFF_WO;

  // weight packing that doesn't conflict with live buffers
  pack_w_kernel<<<dim3(8, 8),  256, 0, stream>>>(Wo,  wop, 512, 512,  1, 9);
  pack_w_kernel<<<dim3(96, 8), 256, 0, stream>>>(c2w, w2p, 512, 6144, 3, 11);

  qkv_kernel<<<8192, 256, 0, stream>>>(x, Wq, Wk, Wv, qbf, kbf, vbf);
  persist_kernel<<<256, 256, 0, stream>>>(p_keys, p_vals, kbf, vbf);
  attn_kernel<<<dim3(64, 8), 256, 0, stream>>>(qbf, kbf, vbf, th_pre, th_post, qbf);
  wo_kernel<<<dim3(128, 8), 256, 0, stream>>>(qbf, wop, bo, x, abf);
  ln_kernel<<<2048, 256, 0, stream>>>(abf, nullptr, ln1g, ln1b, out);   // x1 -> d_out

  // now k/v/a regions are dead -> pack conv1 weights over them
  pack_w_kernel<<<dim3(24, 64), 256, 0, stream>>>(c1w, w1p, 4096, 1536, 3, 9);

  conv1_kernel<<<dim3(128, 32), 256, 0, stream>>>(out, w1p, c1b, hbf);
  conv2_kernel<<<dim3(128, 8),  256, 0, stream>>>(hbf, w2p, c2b, qbf); // f -> R0
  ln_kernel<<<2048, 256, 0, stream>>>(qbf, out, ln2g, ln2b, out);      // in-place over x1
}

// Round 2
// 2113.018 us; speedup vs baseline: 2.3597x; 2.3597x over previous
//
#include <hip/hip_runtime.h>
#include <cstddef>
#include <cstdint>

#define NB   8
#define LQ   1024
#define CH   512
#define HHE  8
#define HDD  64
#define PPM  16
#define LP   1040     // L + P
#define HID  2048

typedef unsigned short ushort_t;
typedef __attribute__((ext_vector_type(8))) short short8;
typedef __attribute__((ext_vector_type(4))) float floatx4;

// ---- workspace layout (float element offsets) ----
static const size_t O_Q    = 0;          // q fp32                (4,194,304)
static const size_t O_K    = 4194304;    // k fp32                (4,259,840)
static const size_t O_V    = 8454144;    // v fp32                (4,259,840)
static const size_t O_AF   = 12713984;   // abf / fbf fp32        (4,194,304)
static const size_t O_AOB  = 16908288;   // aob / x1b bf16 slot   (2,101,248)
static const size_t O_HPAD = 19009536;   // hpad bf16             (8,404,992)
static const size_t O_W1   = 27414528;   // w1 bf16               (3,145,728)
static const size_t O_W2   = 30560256;   // w2 bf16               (1,572,864)
static const size_t O_WO   = 32133120;   // wo bf16               (  131,072)
// hraw bf16 (33,554,432 ushorts) overlays [0 .. 16,777,216) floats (q/k/v/abf, all dead)
// total 32,264,192 floats = 129.06 MB

__device__ __forceinline__ ushort_t f2bf(float f) {
  uint32_t u = __float_as_uint(f);
  u += 0x7FFFu + ((u >> 16) & 1u);
  return (ushort_t)(u >> 16);
}
__device__ __forceinline__ float bf2f(ushort_t h) {
  return __uint_as_float(((uint32_t)h) << 16);
}

__device__ __forceinline__ void async16(ushort_t* lds, const ushort_t* g) {
  __builtin_amdgcn_global_load_lds(
      (const __attribute__((address_space(1))) void*)g,
      (__attribute__((address_space(3))) void*)lds, 16, 0, 0);
}

// ---------------------------------------------------------------------------
// weight pack to bf16 [oc][k], k = dl*IC + ic; src[oc*K + ic*KD + dl]
// ---------------------------------------------------------------------------
__global__ __launch_bounds__(256) void pack_bf16_kernel(
    const float* __restrict__ src, ushort_t* __restrict__ dst,
    int K, int KD, int icShift)
{
  const int oc = blockIdx.x;
  const int icMask = (1 << icShift) - 1;
  for (int k = threadIdx.x; k < K; k += 256) {
    int ic = k & icMask, dl = k >> icShift;
    dst[(size_t)oc * K + k] = f2bf(src[(size_t)oc * K + ic * KD + dl]);
  }
}

// ---------------------------------------------------------------------------
// Generic bf16 MFMA GEMM, 128x128 tile, BK=32, global_load_lds staging.
// A row address: (row>>10)*BS + (row&1023)*P + k   (linear in k; conv padding
// is baked into the padded activation buffer)
// B: bf16 [n][K] rows.
// EPI: 0 = bf16 raw out, 1 = f32 +bias, 2 = f32 +bias+residual
// ---------------------------------------------------------------------------
template<int EPI>
__global__ __launch_bounds__(256, 2) void mfma_gemm(
    const ushort_t* __restrict__ Ab, const ushort_t* __restrict__ Bb,
    int K, int BS, int P, int NOUT,
    const float* __restrict__ bias, const float* __restrict__ res,
    float* __restrict__ outf, ushort_t* __restrict__ outh)
{
  __shared__ ushort_t As[128 * 32];
  __shared__ ushort_t Bs[128 * 32];
  const int t = threadIdx.x;
  const int w = t >> 6, l = t & 63;
  const int m0 = blockIdx.x * 128, n0 = blockIdx.y * 128;

  // staging: wave w stages LDS ushort range [w*1024, w*1024+1024), two 16B
  // instrs per lane; LDS offset o -> row o/32, k o%32 (lane-contiguous, no pad)
  const int sub = l >> 2;          // row within 16-row chunk
  const int kc8 = (l & 3) * 8;     // k offset of this lane's 8 bf16
  const ushort_t* aptr[2];
  const ushort_t* bptr[2];
  #pragma unroll
  for (int c = 0; c < 2; ++c) {
    int arow = m0 + w * 32 + c * 16 + sub;
    aptr[c] = Ab + (size_t)(arow >> 10) * BS + (size_t)(arow & 1023) * P + kc8;
    int brow = n0 + w * 32 + c * 16 + sub;
    bptr[c] = Bb + (size_t)brow * K + kc8;
  }

  const int wm = w >> 1, wn = w & 1;
  const int lm = l & 15, q = l >> 4;
  floatx4 acc[4][4];
  #pragma unroll
  for (int i = 0; i < 4; ++i)
    #pragma unroll
    for (int j = 0; j < 4; ++j)
      acc[i][j] = (floatx4){0.f, 0.f, 0.f, 0.f};

  const int kIters = K >> 5;
  for (int kt = 0; kt < kIters; ++kt) {
    __syncthreads();
    async16(&As[w * 1024 +   0], aptr[0]);
    async16(&As[w * 1024 + 512], aptr[1]);
    async16(&Bs[w * 1024 +   0], bptr[0]);
    async16(&Bs[w * 1024 + 512], bptr[1]);
    aptr[0] += 32; aptr[1] += 32; bptr[0] += 32; bptr[1] += 32;
    __syncthreads();
    short8 af[4], bf[4];
    #pragma unroll
    for (int i = 0; i < 4; ++i)
      af[i] = *(const short8*)&As[(wm * 64 + i * 16 + lm) * 32 + q * 8];
    #pragma unroll
    for (int i = 0; i < 4; ++i)
      bf[i] = *(const short8*)&Bs[(wn * 64 + i * 16 + lm) * 32 + q * 8];
    #pragma unroll
    for (int i = 0; i < 4; ++i)
      #pragma unroll
      for (int j = 0; j < 4; ++j)
        acc[i][j] = __builtin_amdgcn_mfma_f32_16x16x32_bf16(af[i], bf[j], acc[i][j], 0, 0, 0);
  }

  // epilogue: D col = lane&15, row = (lane>>4)*4 + reg   [m89/m91 verified]
  #pragma unroll
  for (int i = 0; i < 4; ++i) {
    #pragma unroll
    for (int j = 0; j < 4; ++j) {
      const int mbase = m0 + wm * 64 + i * 16 + q * 4;
      const int n = n0 + wn * 64 + j * 16 + lm;
      #pragma unroll
      for (int r = 0; r < 4; ++r) {
        const int m = mbase + r;
        float v = acc[i][j][r];
        if (EPI == 0) {
          outh[(size_t)m * NOUT + n] = f2bf(v);
        } else if (EPI == 1) {
          outf[(size_t)m * NOUT + n] = v + bias[n];
        } else {
          outf[(size_t)m * NOUT + n] = v + bias[n] + res[(size_t)m * NOUT + n];
        }
      }
    }
  }
}

// ---------------------------------------------------------------------------
// QKV projection (fp32): per token, q/k/v[h,d] = sum_e W[d,e] * x[h,e]
// ---------------------------------------------------------------------------
__global__ __launch_bounds__(256) void qkv_kernel(
    const float* __restrict__ x,
    const float* __restrict__ Wq, const float* __restrict__ Wk, const float* __restrict__ Wv,
    float* __restrict__ qo, float* __restrict__ ko, float* __restrict__ vo)
{
  __shared__ float xr[512];
  const int tok = blockIdx.x;
  const int n = tok >> 10, l = tok & 1023;
  const int t = threadIdx.x;
  ((float2*)xr)[t] = ((const float2*)(x + (size_t)tok * CH))[t];
  __syncthreads();
  const size_t qbase  = (size_t)tok * CH;
  const size_t kvbase = ((size_t)n * LP + l) * CH;
  #pragma unroll
  for (int half = 0; half < 2; ++half) {
    const int o = t + half * 256;
    const int h = o >> 6, d = o & 63;
    const float* xs = xr + h * 64;
    const float4* wq4 = (const float4*)(Wq + d * 64);
    const float4* wk4 = (const float4*)(Wk + d * 64);
    const float4* wv4 = (const float4*)(Wv + d * 64);
    float sq = 0.f, sk = 0.f, sv = 0.f;
    #pragma unroll
    for (int c = 0; c < 16; ++c) {
      float4 aq = wq4[c], ak = wk4[c], av = wv4[c];
      float x0 = xs[c*4+0], x1 = xs[c*4+1], x2 = xs[c*4+2], x3 = xs[c*4+3];
      sq += aq.x*x0 + aq.y*x1 + aq.z*x2 + aq.w*x3;
      sk += ak.x*x0 + ak.y*x1 + ak.z*x2 + ak.w*x3;
      sv += av.x*x0 + av.y*x1 + av.z*x2 + av.w*x3;
    }
    qo[qbase + o]  = sq;
    ko[kvbase + o] = sk;
    vo[kvbase + o] = sv;
  }
}

__global__ __launch_bounds__(256) void persist_kernel(
    const float* __restrict__ pk, const float* __restrict__ pv,
    float* __restrict__ ko, float* __restrict__ vo)
{
  const int t = blockIdx.x * 256 + threadIdx.x;
  const int n = t >> 13, p = (t >> 9) & 15, c = t & 511, d = c & 63;
  const size_t o = ((size_t)n * LP + LQ + p) * CH + c;
  ko[o] = pk[p * 64 + d];
  vo[o] = pv[p * 64 + d];
}

// ---------------------------------------------------------------------------
// Fused attention (fp32): ALiBi + th_pre + softmax + th_post + AV.
// Writes bf16 output for the Wo MFMA GEMM.
// ---------------------------------------------------------------------------
__global__ __launch_bounds__(256, 2) void attn_kernel(
    const float* __restrict__ q, const float* __restrict__ kb, const float* __restrict__ vb,
    const float* __restrict__ thpre, const float* __restrict__ thpost,
    ushort_t* __restrict__ aob)
{
  __shared__ float qs[16][516];
  __shared__ float ks[16][516];
  __shared__ float at2[16][8][17];
  __shared__ float tpre[64], tpost[64];
  const int n  = blockIdx.y;
  const int q0 = blockIdx.x * 16;
  const int t  = threadIdx.x;

  #pragma unroll
  for (int j = 0; j < 8; ++j) {
    int f = t + 256 * j, r = f >> 7, c4 = f & 127;
    *(float4*)&qs[r][c4 << 2] =
        *(const float4*)&q[((size_t)(n * LQ + q0 + r)) * CH + (c4 << 2)];
  }
  if (t < 64) { tpre[t] = thpre[t]; tpost[t] = thpost[t]; }
  __syncthreads();

  const int tq = t >> 4, l16 = t & 15;
  const int qidx = q0 + tq;
  const float invs = 0.044194173824159216f;
  const float slope[8] = {0.5f, 0.25f, 0.125f, 0.0625f,
                          0.03125f, 0.015625f, 0.0078125f, 0.00390625f};
  float mrun[8], zrun[8];
  #pragma unroll
  for (int g = 0; g < 8; ++g) { mrun[g] = -1e30f; zrun[g] = 0.f; }

  for (int kt = 0; kt < 65; ++kt) {
    const int k0 = kt * 16;
    __syncthreads();
    #pragma unroll
    for (int j = 0; j < 8; ++j) {
      int f = t + 256 * j, r = f >> 7, c4 = f & 127;
      *(float4*)&ks[r][c4 << 2] =
          *(const float4*)&kb[((size_t)(n * LP + k0 + r)) * CH + (c4 << 2)];
    }
    __syncthreads();
    float e[8];
    #pragma unroll
    for (int h = 0; h < 8; ++h) e[h] = 0.f;
    const float4* kr = (const float4*)&ks[l16][0];
    const float4* qr = (const float4*)&qs[tq][0];
    for (int c = 0; c < 16; ++c) {
      #pragma unroll
      for (int h = 0; h < 8; ++h) {
        float4 kv = kr[h * 16 + c], qv = qr[h * 16 + c];
        e[h] += kv.x*qv.x + kv.y*qv.y + kv.z*qv.z + kv.w*qv.w;
      }
    }
    const int kk = k0 + l16;
    if (kk < LQ) {
      float dist = fabsf((float)(qidx - kk));
      #pragma unroll
      for (int h = 0; h < 8; ++h) e[h] -= dist * slope[h];
    }
    #pragma unroll
    for (int g = 0; g < 8; ++g) {
      float s = 0.f;
      #pragma unroll
      for (int h = 0; h < 8; ++h) s += tpre[g * 8 + h] * e[h];
      s *= invs;
      float nm = fmaxf(mrun[g], s);
      zrun[g] = zrun[g] * __expf(mrun[g] - nm) + __expf(s - nm);
      mrun[g] = nm;
    }
  }
  #pragma unroll
  for (int off = 1; off < 16; off <<= 1) {
    #pragma unroll
    for (int g = 0; g < 8; ++g) {
      float mo = __shfl_xor(mrun[g], off);
      float zo = __shfl_xor(zrun[g], off);
      float nm = fmaxf(mrun[g], mo);
      zrun[g] = zrun[g] * __expf(mrun[g] - nm) + zo * __expf(mo - nm);
      mrun[g] = nm;
    }
  }
  float zi[8];
  #pragma unroll
  for (int g = 0; g < 8; ++g) zi[g] = 1.0f / zrun[g];

  float acc[16][2];
  #pragma unroll
  for (int r = 0; r < 16; ++r) { acc[r][0] = 0.f; acc[r][1] = 0.f; }
  const int g2 = t >> 5;
  const int o2 = t << 1;

  for (int kt = 0; kt < 65; ++kt) {
    const int k0 = kt * 16;
    __syncthreads();
    #pragma unroll
    for (int j = 0; j < 8; ++j) {
      int f = t + 256 * j, r = f >> 7, c4 = f & 127;
      *(float4*)&ks[r][c4 << 2] =
          *(const float4*)&kb[((size_t)(n * LP + k0 + r)) * CH + (c4 << 2)];
    }
    __syncthreads();
    float e[8];
    #pragma unroll
    for (int h = 0; h < 8; ++h) e[h] = 0.f;
    const float4* kr = (const float4*)&ks[l16][0];
    const float4* qr = (const float4*)&qs[tq][0];
    for (int c = 0; c < 16; ++c) {
      #pragma unroll
      for (int h = 0; h < 8; ++h) {
        float4 kv = kr[h * 16 + c], qv = qr[h * 16 + c];
        e[h] += kv.x*qv.x + kv.y*qv.y + kv.z*qv.z + kv.w*qv.w;
      }
    }
    const int kk = k0 + l16;
    if (kk < LQ) {
      float dist = fabsf((float)(qidx - kk));
      #pragma unroll
      for (int h = 0; h < 8; ++h) e[h] -= dist * slope[h];
    }
    float p[8];
    #pragma unroll
    for (int g = 0; g < 8; ++g) {
      float s = 0.f;
      #pragma unroll
      for (int h = 0; h < 8; ++h) s += tpre[g * 8 + h] * e[h];
      s *= invs;
      p[g] = __expf(s - mrun[g]) * zi[g];
    }
    #pragma unroll
    for (int gg = 0; gg < 8; ++gg) {
      float a = 0.f;
      #pragma unroll
      for (int g = 0; g < 8; ++g) a += tpost[gg * 8 + g] * p[g];
      at2[tq][gg][l16] = a;
    }
    __syncthreads();
    for (int kk2 = 0; kk2 < 16; ++kk2) {
      float2 v2 = *(const float2*)&vb[((size_t)(n * LP + k0 + kk2)) * CH + o2];
      #pragma unroll
      for (int r = 0; r < 16; ++r) {
        float wgt = at2[r][g2][kk2];
        acc[r][0] += wgt * v2.x;
        acc[r][1] += wgt * v2.y;
      }
    }
  }
  #pragma unroll
  for (int r = 0; r < 16; ++r) {
    ushort2 o;
    o.x = f2bf(acc[r][0]);
    o.y = f2bf(acc[r][1]);
    *(ushort2*)&aob[((size_t)(n * LQ + q0 + r)) * CH + o2] = o;
  }
}

// ---------------------------------------------------------------------------
// swiglu: h = silu(h1+b1)*(h2+b2), raw [8192][4096] bf16 -> padded bf16
// ---------------------------------------------------------------------------
__global__ __launch_bounds__(256) void swiglu_kernel(
    const ushort_t* __restrict__ hraw, const float* __restrict__ bias,
    ushort_t* __restrict__ hpad)
{
  const int tok = blockIdx.x;
  const int n = tok >> 10, l = tok & 1023;
  const size_t src = (size_t)tok * 4096;
  const size_t dst = ((size_t)n * 1026 + l + 1) * 2048;
  for (int c = threadIdx.x; c < 2048; c += 256) {
    float h1 = bf2f(hraw[src + c]) + bias[c];
    float h2 = bf2f(hraw[src + 2048 + c]) + bias[2048 + c];
    float s = h1 / (1.f + __expf(-h1));
    hpad[dst + c] = f2bf(s * h2);
  }
}

// zero the boundary rows of the padded bf16 activation buffers
__global__ __launch_bounds__(256) void zero_pads_kernel(
    ushort_t* __restrict__ x1b, ushort_t* __restrict__ hpad)
{
  const int b = blockIdx.x;
  const int n = b >> 1, side = b & 1;
  const size_t r = (size_t)n * 1026 + side * 1025;
  ushort2 z; z.x = 0; z.y = 0;
  *(ushort2*)&x1b[r * 512 + threadIdx.x * 2] = z;
  #pragma unroll
  for (int i = 0; i < 4; ++i)
    *(ushort2*)&hpad[r * 2048 + (threadIdx.x + 256 * i) * 2] = z;
}

// ---------------------------------------------------------------------------
// LayerNorm (fp32) + optional bf16 padded copy
// ---------------------------------------------------------------------------
__global__ __launch_bounds__(256) void ln_kernel(
    const float* __restrict__ in, const float* __restrict__ res,
    const float* __restrict__ g, const float* __restrict__ b,
    float* __restrict__ outp, ushort_t* __restrict__ bfout)
{
  const int w = threadIdx.x >> 6, lane = threadIdx.x & 63;
  const int tok = blockIdx.x * 4 + w;
  const size_t base = (size_t)tok * CH;
  float4 v0 = *(const float4*)&in[base + (lane << 2)];
  float4 v1 = *(const float4*)&in[base + 256 + (lane << 2)];
  if (res != nullptr) {
    float4 r0 = *(const float4*)&res[base + (lane << 2)];
    float4 r1 = *(const float4*)&res[base + 256 + (lane << 2)];
    v0.x += r0.x; v0.y += r0.y; v0.z += r0.z; v0.w += r0.w;
    v1.x += r1.x; v1.y += r1.y; v1.z += r1.z; v1.w += r1.w;
  }
  float s = v0.x + v0.y + v0.z + v0.w + v1.x + v1.y + v1.z + v1.w;
  #pragma unroll
  for (int off = 32; off > 0; off >>= 1) s += __shfl_xor(s, off);
  const float mu = s * (1.f / 512.f);
  float d0 = v0.x - mu, d1 = v0.y - mu, d2 = v0.z - mu, d3 = v0.w - mu;
  float d4 = v1.x - mu, d5 = v1.y - mu, d6 = v1.z - mu, d7 = v1.w - mu;
  float vs = d0*d0 + d1*d1 + d2*d2 + d3*d3 + d4*d4 + d5*d5 + d6*d6 + d7*d7;
  #pragma unroll
  for (int off = 32; off > 0; off >>= 1) vs += __shfl_xor(vs, off);
  const float r = rsqrtf(vs * (1.f / 512.f) + 1e-5f);
  float4 ga = *(const float4*)&g[(lane << 2)];
  float4 gb = *(const float4*)&g[256 + (lane << 2)];
  float4 ba = *(const float4*)&b[(lane << 2)];
  float4 bb = *(const float4*)&b[256 + (lane << 2)];
  float4 o0, o1;
  o0.x = d0 * r * ga.x + ba.x; o0.y = d1 * r * ga.y + ba.y;
  o0.z = d2 * r * ga.z + ba.z; o0.w = d3 * r * ga.w + ba.w;
  o1.x = d4 * r * gb.x + bb.x; o1.y = d5 * r * gb.y + bb.y;
  o1.z = d6 * r * gb.z + bb.z; o1.w = d7 * r * gb.w + bb.w;
  *(float4*)&outp[base + (lane << 2)] = o0;
  *(float4*)&outp[base + 256 + (lane << 2)] = o1;
  if (bfout != nullptr) {
    const int n = tok >> 10, l = tok & 1023;
    const size_t bb2 = ((size_t)n * 1026 + l + 1) * 512;
    ushort4 u0 = make_ushort4(f2bf(o0.x), f2bf(o0.y), f2bf(o0.z), f2bf(o0.w));
    ushort4 u1 = make_ushort4(f2bf(o1.x), f2bf(o1.y), f2bf(o1.z), f2bf(o1.w));
    *(ushort4*)&bfout[bb2 + (lane << 2)] = u0;
    *(ushort4*)&bfout[bb2 + 256 + (lane << 2)] = u1;
  }
}

// ---------------------------------------------------------------------------
extern "C" void kernel_launch(void* const* d_in, const int* in_sizes, int n_in,
                              void* d_out, int out_size, void* d_ws, size_t ws_size,
                              hipStream_t stream)
{
  (void)in_sizes; (void)n_in; (void)out_size; (void)ws_size;
  const float* x      = (const float*)d_in[0];
  const float* Wq     = (const float*)d_in[1];
  const float* Wk     = (const float*)d_in[2];
  const float* Wv     = (const float*)d_in[3];
  const float* Wo     = (const float*)d_in[4];
  const float* bo     = (const float*)d_in[5];
  const float* th_pre = (const float*)d_in[6];
  const float* th_post= (const float*)d_in[7];
  const float* p_keys = (const float*)d_in[8];
  const float* p_vals = (const float*)d_in[9];
  const float* c1w    = (const float*)d_in[10];
  const float* c1b    = (const float*)d_in[11];
  const float* c2w    = (const float*)d_in[12];
  const float* c2b    = (const float*)d_in[13];
  const float* ln1g   = (const float*)d_in[14];
  const float* ln1b   = (const float*)d_in[15];
  const float* ln2g   = (const float*)d_in[16];
  const float* ln2b   = (const float*)d_in[17];

  float* ws  = (float*)d_ws;
  float* out = (float*)d_out;

  float* qbf = ws + O_Q;
  float* kbf = ws + O_K;
  float* vbf = ws + O_V;
  float* abf = ws + O_AF;
  float* fbf = abf;                       // conv2 out reuses abf slot
  ushort_t* aob  = (ushort_t*)(ws + O_AOB);
  ushort_t* x1b  = aob;                   // LN1 bf16 overwrites dead aob
  ushort_t* hpad = (ushort_t*)(ws + O_HPAD);
  ushort_t* hraw = (ushort_t*)ws;         // overlays dead q/k/v/abf
  ushort_t* w1p  = (ushort_t*)(ws + O_W1);
  ushort_t* w2p  = (ushort_t*)(ws + O_W2);
  ushort_t* wop  = (ushort_t*)(ws + O_WO);

  // weight packs (bf16, [n][k] with k = dl*IC + ic)
  pack_bf16_kernel<<<4096, 256, 0, stream>>>(c1w, w1p, 1536, 3, 9);
  pack_bf16_kernel<<<512,  256, 0, stream>>>(c2w, w2p, 6144, 3, 11);
  pack_bf16_kernel<<<512,  256, 0, stream>>>(Wo,  wop, 512,  1, 9);

  qkv_kernel<<<8192, 256, 0, stream>>>(x, Wq, Wk, Wv, qbf, kbf, vbf);
  persist_kernel<<<256, 256, 0, stream>>>(p_keys, p_vals, kbf, vbf);
  attn_kernel<<<dim3(64, 8), 256, 0, stream>>>(qbf, kbf, vbf, th_pre, th_post, aob);

  // Wo: M=8192 N=512 K=512, +bias +residual(x) -> abf fp32
  mfma_gemm<2><<<dim3(64, 4), 256, 0, stream>>>(
      aob, wop, 512, 1024 * 512, 512, 512, bo, x, abf, nullptr);

  ln_kernel<<<2048, 256, 0, stream>>>(abf, nullptr, ln1g, ln1b, out, x1b);
  zero_pads_kernel<<<16, 256, 0, stream>>>(x1b, hpad);

  // conv1: M=8192 N=4096 K=1536 -> hraw bf16
  mfma_gemm<0><<<dim3(64, 32), 256, 0, stream>>>(
      x1b, w1p, 1536, 1026 * 512, 512, 4096, nullptr, nullptr, nullptr, hraw);

  swiglu_kernel<<<8192, 256, 0, stream>>>(hraw, c1b, hpad);

  // conv2: M=8192 N=512 K=6144, +bias -> fbf fp32
  mfma_gemm<1><<<dim3(64, 4), 256, 0, stream>>>(
      hpad, w2p, 6144, 1026 * 2048, 2048, 512, c2b, nullptr, fbf, nullptr);

  ln_kernel<<<2048, 256, 0, stream>>>(fbf, out, ln2g, ln2b, out, nullptr);
}

// Round 3
// 1366.447 us; speedup vs baseline: 3.6489x; 1.5464x over previous
//
#include <hip/hip_runtime.h>
#include <cstddef>
#include <cstdint>

#define NB   8
#define LQ   1024
#define CH   512
#define HHE  8
#define HDD  64
#define PPM  16
#define LP   1040     // L + P
#define HID  2048

typedef unsigned short ushort_t;
typedef __attribute__((ext_vector_type(8))) short short8;
typedef __attribute__((ext_vector_type(4))) float floatx4;

// ---- workspace layout (float element offsets) ----
static const size_t O_QB   = 0;          // Qb bf16   (2,097,152 fl)
static const size_t O_KB   = 2097152;    // Kb bf16   (2,129,920 fl)
static const size_t O_VB   = 4227072;    // Vb bf16   (2,129,920 fl)
static const size_t O_VT   = 6356992;    // VT bf16   (2,129,920 fl)
static const size_t O_AOB  = 8486912;    // aob bf16  (2,097,152 fl)
static const size_t O_AF   = 10584064;   // abf/fbf fp32 (4,194,304 fl)
// hraw bf16 overlays floats [0 .. 16,777,216) -- all of the above are dead then
static const size_t O_X1B  = 16777216;   // x1b padded bf16 (2,101,248 fl)
static const size_t O_HPAD = 18878464;   // hpad bf16 (8,404,992 fl)
static const size_t O_W1   = 27283456;   // w1 bf16   (3,145,728 fl)
static const size_t O_W2   = 30429184;   // w2 bf16   (1,572,864 fl)
static const size_t O_WO   = 32002048;   // wo bf16   (131,072 fl)
// total 32,133,120 floats = 128.5 MB

__device__ __forceinline__ ushort_t f2bf(float f) {
  uint32_t u = __float_as_uint(f);
  u += 0x7FFFu + ((u >> 16) & 1u);
  return (ushort_t)(u >> 16);
}
__device__ __forceinline__ float bf2f(ushort_t h) {
  return __uint_as_float(((uint32_t)h) << 16);
}

__device__ __forceinline__ void async16(ushort_t* lds, const ushort_t* g) {
  __builtin_amdgcn_global_load_lds(
      (const __attribute__((address_space(1))) void*)g,
      (__attribute__((address_space(3))) void*)lds, 16, 0, 0);
}

// ---------------------------------------------------------------------------
// weight pack to bf16 [oc][k], k = dl*IC + ic; src[oc*K + ic*KD + dl]
// ---------------------------------------------------------------------------
__global__ __launch_bounds__(256) void pack_bf16_kernel(
    const float* __restrict__ src, ushort_t* __restrict__ dst,
    int K, int KD, int icShift)
{
  const int oc = blockIdx.x;
  const int icMask = (1 << icShift) - 1;
  for (int k = threadIdx.x; k < K; k += 256) {
    int ic = k & icMask, dl = k >> icShift;
    dst[(size_t)oc * K + k] = f2bf(src[(size_t)oc * K + ic * KD + dl]);
  }
}

// ---------------------------------------------------------------------------
// Generic bf16 MFMA GEMM, 128x128 tile, BK=32, global_load_lds staging.
// ---------------------------------------------------------------------------
template<int EPI>
__global__ __launch_bounds__(256, 2) void mfma_gemm(
    const ushort_t* __restrict__ Ab, const ushort_t* __restrict__ Bb,
    int K, int BS, int P, int NOUT,
    const float* __restrict__ bias, const float* __restrict__ res,
    float* __restrict__ outf, ushort_t* __restrict__ outh)
{
  __shared__ ushort_t As[128 * 32];
  __shared__ ushort_t Bs[128 * 32];
  const int t = threadIdx.x;
  const int w = t >> 6, l = t & 63;
  const int m0 = blockIdx.x * 128, n0 = blockIdx.y * 128;

  const int sub = l >> 2;
  const int kc8 = (l & 3) * 8;
  const ushort_t* aptr[2];
  const ushort_t* bptr[2];
  #pragma unroll
  for (int c = 0; c < 2; ++c) {
    int arow = m0 + w * 32 + c * 16 + sub;
    aptr[c] = Ab + (size_t)(arow >> 10) * BS + (size_t)(arow & 1023) * P + kc8;
    int brow = n0 + w * 32 + c * 16 + sub;
    bptr[c] = Bb + (size_t)brow * K + kc8;
  }

  const int wm = w >> 1, wn = w & 1;
  const int lm = l & 15, q = l >> 4;
  floatx4 acc[4][4];
  #pragma unroll
  for (int i = 0; i < 4; ++i)
    #pragma unroll
    for (int j = 0; j < 4; ++j)
      acc[i][j] = (floatx4){0.f, 0.f, 0.f, 0.f};

  const int kIters = K >> 5;
  for (int kt = 0; kt < kIters; ++kt) {
    __syncthreads();
    async16(&As[w * 1024 +   0], aptr[0]);
    async16(&As[w * 1024 + 512], aptr[1]);
    async16(&Bs[w * 1024 +   0], bptr[0]);
    async16(&Bs[w * 1024 + 512], bptr[1]);
    aptr[0] += 32; aptr[1] += 32; bptr[0] += 32; bptr[1] += 32;
    __syncthreads();
    short8 af[4], bf[4];
    #pragma unroll
    for (int i = 0; i < 4; ++i)
      af[i] = *(const short8*)&As[(wm * 64 + i * 16 + lm) * 32 + q * 8];
    #pragma unroll
    for (int i = 0; i < 4; ++i)
      bf[i] = *(const short8*)&Bs[(wn * 64 + i * 16 + lm) * 32 + q * 8];
    #pragma unroll
    for (int i = 0; i < 4; ++i)
      #pragma unroll
      for (int j = 0; j < 4; ++j)
        acc[i][j] = __builtin_amdgcn_mfma_f32_16x16x32_bf16(af[i], bf[j], acc[i][j], 0, 0, 0);
  }

  #pragma unroll
  for (int i = 0; i < 4; ++i) {
    #pragma unroll
    for (int j = 0; j < 4; ++j) {
      const int mbase = m0 + wm * 64 + i * 16 + q * 4;
      const int n = n0 + wn * 64 + j * 16 + lm;
      #pragma unroll
      for (int r = 0; r < 4; ++r) {
        const int m = mbase + r;
        float v = acc[i][j][r];
        if (EPI == 0) {
          outh[(size_t)m * NOUT + n] = f2bf(v);
        } else if (EPI == 1) {
          outf[(size_t)m * NOUT + n] = v + bias[n];
        } else {
          outf[(size_t)m * NOUT + n] = v + bias[n] + res[(size_t)m * NOUT + n];
        }
      }
    }
  }
}

// ---------------------------------------------------------------------------
// QKV projection -> bf16 outputs.
// ---------------------------------------------------------------------------
__global__ __launch_bounds__(256) void qkv_kernel(
    const float* __restrict__ x,
    const float* __restrict__ Wq, const float* __restrict__ Wk, const float* __restrict__ Wv,
    ushort_t* __restrict__ qo, ushort_t* __restrict__ ko, ushort_t* __restrict__ vo)
{
  __shared__ float xr[512];
  const int tok = blockIdx.x;
  const int n = tok >> 10, l = tok & 1023;
  const int t = threadIdx.x;
  ((float2*)xr)[t] = ((const float2*)(x + (size_t)tok * CH))[t];
  __syncthreads();
  const size_t qbase  = (size_t)tok * CH;
  const size_t kvbase = ((size_t)n * LP + l) * CH;
  #pragma unroll
  for (int half = 0; half < 2; ++half) {
    const int o = t + half * 256;
    const int h = o >> 6, d = o & 63;
    const float* xs = xr + h * 64;
    const float4* wq4 = (const float4*)(Wq + d * 64);
    const float4* wk4 = (const float4*)(Wk + d * 64);
    const float4* wv4 = (const float4*)(Wv + d * 64);
    float sq = 0.f, sk = 0.f, sv = 0.f;
    #pragma unroll
    for (int c = 0; c < 16; ++c) {
      float4 aq = wq4[c], ak = wk4[c], av = wv4[c];
      float x0 = xs[c*4+0], x1 = xs[c*4+1], x2 = xs[c*4+2], x3 = xs[c*4+3];
      sq += aq.x*x0 + aq.y*x1 + aq.z*x2 + aq.w*x3;
      sk += ak.x*x0 + ak.y*x1 + ak.z*x2 + ak.w*x3;
      sv += av.x*x0 + av.y*x1 + av.z*x2 + av.w*x3;
    }
    qo[qbase + o]  = f2bf(sq);
    ko[kvbase + o] = f2bf(sk);
    vo[kvbase + o] = f2bf(sv);
  }
}

__global__ __launch_bounds__(256) void persist_kernel(
    const float* __restrict__ pk, const float* __restrict__ pv,
    ushort_t* __restrict__ ko, ushort_t* __restrict__ vo)
{
  const int t = blockIdx.x * 256 + threadIdx.x;
  const int n = t >> 13, p = (t >> 9) & 15, c = t & 511, d = c & 63;
  const size_t o = ((size_t)n * LP + LQ + p) * CH + c;
  ko[o] = f2bf(pk[p * 64 + d]);
  vo[o] = f2bf(pv[p * 64 + d]);
}

// ---------------------------------------------------------------------------
// V transpose: Vb [n][k(1040)][512] -> VT [n][d(512)][1040]
// grid (65, 8)
// ---------------------------------------------------------------------------
__global__ __launch_bounds__(256) void vtrans_kernel(
    const ushort_t* __restrict__ Vb, ushort_t* __restrict__ VT)
{
  __shared__ ushort_t Ls[16 * 520];
  const int n = blockIdx.y, k0 = blockIdx.x * 16;
  const int t = threadIdx.x;
  const int r = t >> 4;
  {
    const ushort_t* src = Vb + ((size_t)(n * LP + k0 + r)) * 512 + (t & 15) * 8;
    ushort_t* dst = &Ls[r * 520 + (t & 15) * 8];
    #pragma unroll
    for (int it = 0; it < 4; ++it)
      *(short8*)(dst + it * 128) = *(const short8*)(src + it * 128);
  }
  __syncthreads();
  #pragma unroll
  for (int rep = 0; rep < 2; ++rep) {
    const int d = t + rep * 256;
    short8 v0, v1;
    #pragma unroll
    for (int j = 0; j < 8; ++j) {
      v0[j] = (short)Ls[j * 520 + d];
      v1[j] = (short)Ls[(8 + j) * 520 + d];
    }
    ushort_t* dst = VT + ((size_t)(n * 512 + d)) * LP + k0;
    *(short8*)(dst)     = v0;
    *(short8*)(dst + 8) = v1;
  }
}

// ---------------------------------------------------------------------------
// MFMA flash attention with talking heads + ALiBi.
// Block: (q-tile 16, n). 4 waves; wave w owns softmax groups {2w,2w+1} and
// output head-groups {2w,2w+1}. Two passes: (1) m,z stats; (2) P + AV.
// ---------------------------------------------------------------------------
__global__ __launch_bounds__(256, 2) void attn_mfma(
    const ushort_t* __restrict__ Qb, const ushort_t* __restrict__ Kb,
    const ushort_t* __restrict__ VT,
    const float* __restrict__ thpre, const float* __restrict__ thpost,
    ushort_t* __restrict__ aob)
{
  __shared__ ushort_t Ks[16 * 520];     // K tile [key][d], row pad 8
  __shared__ ushort_t Vt[512 * 40];     // V^T tile [d][k-pair 32], row pad 8
  __shared__ float   Ps[8 * 16 * 36];   // P [g][q][k-pair 32], row pad 4
  const int n = blockIdx.y, q0 = blockIdx.x * 16;
  const int t = threadIdx.x;
  const int w = t >> 6, l = t & 63;
  const int lm = l & 15, quad = l >> 4;
  const float invs = 0.044194173824159216f;  // 1/sqrt(512)

  // persistent Q fragments: A-frag lane&15 = q-row, quad*8+j = d-offset
  short8 qf[16];
  {
    const ushort_t* qrow = Qb + ((size_t)(n * LQ + q0 + lm)) * 512 + quad * 8;
    #pragma unroll
    for (int h = 0; h < 8; ++h) {
      qf[h * 2 + 0] = *(const short8*)(qrow + h * 64);
      qf[h * 2 + 1] = *(const short8*)(qrow + h * 64 + 32);
    }
  }
  float tps[2][8], psl[2], tpo[2][8];
  #pragma unroll
  for (int gg = 0; gg < 2; ++gg) {
    const int g = w * 2 + gg;
    float ps = 0.f;
    #pragma unroll
    for (int h = 0; h < 8; ++h) {
      float tv = thpre[g * 8 + h] * invs;
      tps[gg][h] = tv;
      ps += tv * (1.0f / (float)(2 << h));   // slope_h = 2^-(h+1)
      tpo[gg][h] = thpost[g * 8 + h];
    }
    psl[gg] = ps;
  }

  float m_[2][4], z_[2][4];
  #pragma unroll
  for (int gg = 0; gg < 2; ++gg)
    #pragma unroll
    for (int r = 0; r < 4; ++r) { m_[gg][r] = -1e30f; z_[gg][r] = 0.f; }

  // ---------------- pass 1: stats ----------------
  for (int step = 0; step < 65; ++step) {
    const int k0 = step * 16;
    {
      const ushort_t* src = Kb + ((size_t)(n * LP + k0 + (t >> 4))) * 512 + (t & 15) * 8;
      ushort_t* dst = &Ks[(t >> 4) * 520 + (t & 15) * 8];
      #pragma unroll
      for (int it = 0; it < 4; ++it)
        *(short8*)(dst + it * 128) = *(const short8*)(src + it * 128);
    }
    __syncthreads();
    floatx4 ef[8];
    {
      const ushort_t* kbase = &Ks[lm * 520 + quad * 8];
      #pragma unroll
      for (int h = 0; h < 8; ++h) {
        floatx4 e = (floatx4){0.f, 0.f, 0.f, 0.f};
        short8 b0 = *(const short8*)(kbase + h * 64);
        short8 b1 = *(const short8*)(kbase + h * 64 + 32);
        e = __builtin_amdgcn_mfma_f32_16x16x32_bf16(qf[h * 2 + 0], b0, e, 0, 0, 0);
        e = __builtin_amdgcn_mfma_f32_16x16x32_bf16(qf[h * 2 + 1], b1, e, 0, 0, 0);
        ef[h] = e;
      }
    }
    const bool alibi = (step < 64);
    #pragma unroll
    for (int r = 0; r < 4; ++r) {
      const float dist = fabsf((float)(q0 + quad * 4 + r - (k0 + lm)));
      #pragma unroll
      for (int gg = 0; gg < 2; ++gg) {
        float s = tps[gg][0] * ef[0][r];
        #pragma unroll
        for (int h = 1; h < 8; ++h) s += tps[gg][h] * ef[h][r];
        if (alibi) s -= dist * psl[gg];
        const float mo = m_[gg][r];
        const float mn = fmaxf(mo, s);
        z_[gg][r] = z_[gg][r] * __expf(mo - mn) + __expf(s - mn);
        m_[gg][r] = mn;
      }
    }
    __syncthreads();
  }
  // combine per-column partials across the 16 lanes of each quad group
  #pragma unroll
  for (int off = 1; off < 16; off <<= 1) {
    #pragma unroll
    for (int gg = 0; gg < 2; ++gg)
      #pragma unroll
      for (int r = 0; r < 4; ++r) {
        const float mo = __shfl_xor(m_[gg][r], off);
        const float zo = __shfl_xor(z_[gg][r], off);
        const float mn = fmaxf(m_[gg][r], mo);
        z_[gg][r] = z_[gg][r] * __expf(m_[gg][r] - mn) + zo * __expf(mo - mn);
        m_[gg][r] = mn;
      }
  }
  float zi[2][4];
  #pragma unroll
  for (int gg = 0; gg < 2; ++gg)
    #pragma unroll
    for (int r = 0; r < 4; ++r) zi[gg][r] = 1.0f / z_[gg][r];

  // ---------------- pass 2: P + AV ----------------
  floatx4 o_[2][4];
  #pragma unroll
  for (int gg = 0; gg < 2; ++gg)
    #pragma unroll
    for (int ch = 0; ch < 4; ++ch) o_[gg][ch] = (floatx4){0.f, 0.f, 0.f, 0.f};

  for (int pair = 0; pair < 33; ++pair) {
    const int nsub = (pair == 32) ? 1 : 2;
    for (int sub = 0; sub < nsub; ++sub) {
      const int step = pair * 2 + sub, k0 = step * 16;
      {
        const ushort_t* src = Kb + ((size_t)(n * LP + k0 + (t >> 4))) * 512 + (t & 15) * 8;
        ushort_t* dst = &Ks[(t >> 4) * 520 + (t & 15) * 8];
        #pragma unroll
        for (int it = 0; it < 4; ++it)
          *(short8*)(dst + it * 128) = *(const short8*)(src + it * 128);
      }
      #pragma unroll
      for (int rep = 0; rep < 2; ++rep) {
        const int d = t + rep * 256;
        const ushort_t* src = VT + ((size_t)(n * 512 + d)) * LP + k0;
        ushort_t* dst = &Vt[d * 40 + sub * 16];
        *(short8*)(dst)     = *(const short8*)(src);
        *(short8*)(dst + 8) = *(const short8*)(src + 8);
      }
      __syncthreads();
      floatx4 ef[8];
      {
        const ushort_t* kbase = &Ks[lm * 520 + quad * 8];
        #pragma unroll
        for (int h = 0; h < 8; ++h) {
          floatx4 e = (floatx4){0.f, 0.f, 0.f, 0.f};
          short8 b0 = *(const short8*)(kbase + h * 64);
          short8 b1 = *(const short8*)(kbase + h * 64 + 32);
          e = __builtin_amdgcn_mfma_f32_16x16x32_bf16(qf[h * 2 + 0], b0, e, 0, 0, 0);
          e = __builtin_amdgcn_mfma_f32_16x16x32_bf16(qf[h * 2 + 1], b1, e, 0, 0, 0);
          ef[h] = e;
        }
      }
      const bool alibi = (step < 64);
      #pragma unroll
      for (int r = 0; r < 4; ++r) {
        const float dist = fabsf((float)(q0 + quad * 4 + r - (k0 + lm)));
        #pragma unroll
        for (int gg = 0; gg < 2; ++gg) {
          float s = tps[gg][0] * ef[0][r];
          #pragma unroll
          for (int h = 1; h < 8; ++h) s += tps[gg][h] * ef[h][r];
          if (alibi) s -= dist * psl[gg];
          const float p = __expf(s - m_[gg][r]) * zi[gg][r];
          Ps[((w * 2 + gg) * 16 + quad * 4 + r) * 36 + sub * 16 + lm] = p;
          if (pair == 32)
            Ps[((w * 2 + gg) * 16 + quad * 4 + r) * 36 + 16 + lm] = 0.f;
        }
      }
      __syncthreads();
    }
    // AV: post-mix during A-frag assembly, then 16x16x32 MFMA (K = 32 keys)
    float pm[2][8];
    #pragma unroll
    for (int gg = 0; gg < 2; ++gg)
      #pragma unroll
      for (int j = 0; j < 8; ++j) pm[gg][j] = 0.f;
    #pragma unroll
    for (int g = 0; g < 8; ++g) {
      const float4 pa = *(const float4*)&Ps[(g * 16 + lm) * 36 + quad * 8];
      const float4 pb = *(const float4*)&Ps[(g * 16 + lm) * 36 + quad * 8 + 4];
      #pragma unroll
      for (int gg = 0; gg < 2; ++gg) {
        const float tw = tpo[gg][g];
        pm[gg][0] += tw * pa.x; pm[gg][1] += tw * pa.y;
        pm[gg][2] += tw * pa.z; pm[gg][3] += tw * pa.w;
        pm[gg][4] += tw * pb.x; pm[gg][5] += tw * pb.y;
        pm[gg][6] += tw * pb.z; pm[gg][7] += tw * pb.w;
      }
    }
    short8 pk[2];
    #pragma unroll
    for (int gg = 0; gg < 2; ++gg)
      #pragma unroll
      for (int j = 0; j < 8; ++j) pk[gg][j] = (short)f2bf(pm[gg][j]);
    #pragma unroll
    for (int gg = 0; gg < 2; ++gg) {
      #pragma unroll
      for (int ch = 0; ch < 4; ++ch) {
        const int d = (w * 2 + gg) * 64 + ch * 16 + lm;
        const short8 vf = *(const short8*)&Vt[d * 40 + quad * 8];
        o_[gg][ch] = __builtin_amdgcn_mfma_f32_16x16x32_bf16(pk[gg], vf, o_[gg][ch], 0, 0, 0);
      }
    }
    __syncthreads();
  }

  // epilogue
  #pragma unroll
  for (int gg = 0; gg < 2; ++gg)
    #pragma unroll
    for (int ch = 0; ch < 4; ++ch) {
      const int d = (w * 2 + gg) * 64 + ch * 16 + lm;
      #pragma unroll
      for (int r = 0; r < 4; ++r)
        aob[((size_t)(n * LQ + q0 + quad * 4 + r)) * 512 + d] = f2bf(o_[gg][ch][r]);
    }
}

// ---------------------------------------------------------------------------
// swiglu: h = silu(h1+b1)*(h2+b2), raw [8192][4096] bf16 -> padded bf16
// ---------------------------------------------------------------------------
__global__ __launch_bounds__(256) void swiglu_kernel(
    const ushort_t* __restrict__ hraw, const float* __restrict__ bias,
    ushort_t* __restrict__ hpad)
{
  const int tok = blockIdx.x;
  const int n = tok >> 10, l = tok & 1023;
  const size_t src = (size_t)tok * 4096;
  const size_t dst = ((size_t)n * 1026 + l + 1) * 2048;
  for (int c = threadIdx.x; c < 2048; c += 256) {
    float h1 = bf2f(hraw[src + c]) + bias[c];
    float h2 = bf2f(hraw[src + 2048 + c]) + bias[2048 + c];
    float s = h1 / (1.f + __expf(-h1));
    hpad[dst + c] = f2bf(s * h2);
  }
}

__global__ __launch_bounds__(256) void zero_pads_kernel(
    ushort_t* __restrict__ x1b, ushort_t* __restrict__ hpad)
{
  const int b = blockIdx.x;
  const int n = b >> 1, side = b & 1;
  const size_t r = (size_t)n * 1026 + side * 1025;
  ushort2 z; z.x = 0; z.y = 0;
  *(ushort2*)&x1b[r * 512 + threadIdx.x * 2] = z;
  #pragma unroll
  for (int i = 0; i < 4; ++i)
    *(ushort2*)&hpad[r * 2048 + (threadIdx.x + 256 * i) * 2] = z;
}

// ---------------------------------------------------------------------------
// LayerNorm (fp32) + optional bf16 padded copy
// ---------------------------------------------------------------------------
__global__ __launch_bounds__(256) void ln_kernel(
    const float* __restrict__ in, const float* __restrict__ res,
    const float* __restrict__ g, const float* __restrict__ b,
    float* __restrict__ outp, ushort_t* __restrict__ bfout)
{
  const int w = threadIdx.x >> 6, lane = threadIdx.x & 63;
  const int tok = blockIdx.x * 4 + w;
  const size_t base = (size_t)tok * CH;
  float4 v0 = *(const float4*)&in[base + (lane << 2)];
  float4 v1 = *(const float4*)&in[base + 256 + (lane << 2)];
  if (res != nullptr) {
    float4 r0 = *(const float4*)&res[base + (lane << 2)];
    float4 r1 = *(const float4*)&res[base + 256 + (lane << 2)];
    v0.x += r0.x; v0.y += r0.y; v0.z += r0.z; v0.w += r0.w;
    v1.x += r1.x; v1.y += r1.y; v1.z += r1.z; v1.w += r1.w;
  }
  float s = v0.x + v0.y + v0.z + v0.w + v1.x + v1.y + v1.z + v1.w;
  #pragma unroll
  for (int off = 32; off > 0; off >>= 1) s += __shfl_xor(s, off);
  const float mu = s * (1.f / 512.f);
  float d0 = v0.x - mu, d1 = v0.y - mu, d2 = v0.z - mu, d3 = v0.w - mu;
  float d4 = v1.x - mu, d5 = v1.y - mu, d6 = v1.z - mu, d7 = v1.w - mu;
  float vs = d0*d0 + d1*d1 + d2*d2 + d3*d3 + d4*d4 + d5*d5 + d6*d6 + d7*d7;
  #pragma unroll
  for (int off = 32; off > 0; off >>= 1) vs += __shfl_xor(vs, off);
  const float r = rsqrtf(vs * (1.f / 512.f) + 1e-5f);
  float4 ga = *(const float4*)&g[(lane << 2)];
  float4 gb = *(const float4*)&g[256 + (lane << 2)];
  float4 ba = *(const float4*)&b[(lane << 2)];
  float4 bb = *(const float4*)&b[256 + (lane << 2)];
  float4 o0, o1;
  o0.x = d0 * r * ga.x + ba.x; o0.y = d1 * r * ga.y + ba.y;
  o0.z = d2 * r * ga.z + ba.z; o0.w = d3 * r * ga.w + ba.w;
  o1.x = d4 * r * gb.x + bb.x; o1.y = d5 * r * gb.y + bb.y;
  o1.z = d6 * r * gb.z + bb.z; o1.w = d7 * r * gb.w + bb.w;
  *(float4*)&outp[base + (lane << 2)] = o0;
  *(float4*)&outp[base + 256 + (lane << 2)] = o1;
  if (bfout != nullptr) {
    const int n = tok >> 10, ll = tok & 1023;
    const size_t bb2 = ((size_t)n * 1026 + ll + 1) * 512;
    ushort4 u0 = make_ushort4(f2bf(o0.x), f2bf(o0.y), f2bf(o0.z), f2bf(o0.w));
    ushort4 u1 = make_ushort4(f2bf(o1.x), f2bf(o1.y), f2bf(o1.z), f2bf(o1.w));
    *(ushort4*)&bfout[bb2 + (lane << 2)] = u0;
    *(ushort4*)&bfout[bb2 + 256 + (lane << 2)] = u1;
  }
}

// ---------------------------------------------------------------------------
extern "C" void kernel_launch(void* const* d_in, const int* in_sizes, int n_in,
                              void* d_out, int out_size, void* d_ws, size_t ws_size,
                              hipStream_t stream)
{
  (void)in_sizes; (void)n_in; (void)out_size; (void)ws_size;
  const float* x      = (const float*)d_in[0];
  const float* Wq     = (const float*)d_in[1];
  const float* Wk     = (const float*)d_in[2];
  const float* Wv     = (const float*)d_in[3];
  const float* Wo     = (const float*)d_in[4];
  const float* bo     = (const float*)d_in[5];
  const float* th_pre = (const float*)d_in[6];
  const float* th_post= (const float*)d_in[7];
  const float* p_keys = (const float*)d_in[8];
  const float* p_vals = (const float*)d_in[9];
  const float* c1w    = (const float*)d_in[10];
  const float* c1b    = (const float*)d_in[11];
  const float* c2w    = (const float*)d_in[12];
  const float* c2b    = (const float*)d_in[13];
  const float* ln1g   = (const float*)d_in[14];
  const float* ln1b   = (const float*)d_in[15];
  const float* ln2g   = (const float*)d_in[16];
  const float* ln2b   = (const float*)d_in[17];

  float* ws  = (float*)d_ws;
  float* out = (float*)d_out;

  ushort_t* Qb   = (ushort_t*)(ws + O_QB);
  ushort_t* Kb   = (ushort_t*)(ws + O_KB);
  ushort_t* Vb   = (ushort_t*)(ws + O_VB);
  ushort_t* VT   = (ushort_t*)(ws + O_VT);
  ushort_t* aob  = (ushort_t*)(ws + O_AOB);
  float*    abf  = ws + O_AF;
  float*    fbf  = abf;
  ushort_t* x1b  = (ushort_t*)(ws + O_X1B);
  ushort_t* hpad = (ushort_t*)(ws + O_HPAD);
  ushort_t* hraw = (ushort_t*)ws;         // overlays dead attn buffers
  ushort_t* w1p  = (ushort_t*)(ws + O_W1);
  ushort_t* w2p  = (ushort_t*)(ws + O_W2);
  ushort_t* wop  = (ushort_t*)(ws + O_WO);

  pack_bf16_kernel<<<4096, 256, 0, stream>>>(c1w, w1p, 1536, 3, 9);
  pack_bf16_kernel<<<512,  256, 0, stream>>>(c2w, w2p, 6144, 3, 11);
  pack_bf16_kernel<<<512,  256, 0, stream>>>(Wo,  wop, 512,  1, 9);

  qkv_kernel<<<8192, 256, 0, stream>>>(x, Wq, Wk, Wv, Qb, Kb, Vb);
  persist_kernel<<<256, 256, 0, stream>>>(p_keys, p_vals, Kb, Vb);
  vtrans_kernel<<<dim3(65, 8), 256, 0, stream>>>(Vb, VT);

  attn_mfma<<<dim3(64, 8), 256, 0, stream>>>(Qb, Kb, VT, th_pre, th_post, aob);

  // Wo: M=8192 N=512 K=512, +bias +residual(x) -> abf fp32
  mfma_gemm<2><<<dim3(64, 4), 256, 0, stream>>>(
      aob, wop, 512, 1024 * 512, 512, 512, bo, x, abf, nullptr);

  ln_kernel<<<2048, 256, 0, stream>>>(abf, nullptr, ln1g, ln1b, out, x1b);
  zero_pads_kernel<<<16, 256, 0, stream>>>(x1b, hpad);

  // conv1: M=8192 N=4096 K=1536 -> hraw bf16
  mfma_gemm<0><<<dim3(64, 32), 256, 0, stream>>>(
      x1b, w1p, 1536, 1026 * 512, 512, 4096, nullptr, nullptr, nullptr, hraw);

  swiglu_kernel<<<8192, 256, 0, stream>>>(hraw, c1b, hpad);

  // conv2: M=8192 N=512 K=6144, +bias -> fbf fp32
  mfma_gemm<1><<<dim3(64, 4), 256, 0, stream>>>(
      hpad, w2p, 6144, 1026 * 2048, 2048, 512, c2b, nullptr, fbf, nullptr);

  ln_kernel<<<2048, 256, 0, stream>>>(fbf, out, ln2g, ln2b, out, nullptr);
}

// Round 4
// 673.980 us; speedup vs baseline: 7.3979x; 2.0274x over previous
//
#include <hip/hip_runtime.h>
#include <cstddef>
#include <cstdint>

#define NB   8
#define LQ   1024
#define CH   512
#define HHE  8
#define HDD  64
#define PPM  16
#define LP   1040     // L + P
#define HID  2048

typedef unsigned short ushort_t;
typedef __attribute__((ext_vector_type(8))) short short8;
typedef __attribute__((ext_vector_type(4))) float floatx4;

// ---- workspace layout (float element offsets) ----
static const size_t O_QB   = 0;          // Qb bf16   (2,097,152 fl)
static const size_t O_KB   = 2097152;    // Kb bf16   (2,129,920 fl)
static const size_t O_VB   = 4227072;    // Vb bf16   (2,129,920 fl)
static const size_t O_VT   = 6356992;    // VT bf16   (2,129,920 fl)
static const size_t O_AOB  = 8486912;    // aob bf16  (2,097,152 fl)
static const size_t O_AF   = 10584064;   // abf/fbf fp32 (4,194,304 fl)
// hraw bf16 overlays floats [0 .. 16,777,216) -- all of the above are dead then
static const size_t O_X1B  = 16777216;   // x1b padded bf16 (2,101,248 fl)
static const size_t O_HPAD = 18878464;   // hpad bf16 (8,404,992 fl)
static const size_t O_W1   = 27283456;   // w1 bf16   (3,145,728 fl)
static const size_t O_W2   = 30429184;   // w2 bf16   (1,572,864 fl)
static const size_t O_WO   = 32002048;   // wo bf16   (131,072 fl)
// total 32,133,120 floats = 128.5 MB

__device__ __forceinline__ ushort_t f2bf(float f) {
  uint32_t u = __float_as_uint(f);
  u += 0x7FFFu + ((u >> 16) & 1u);
  return (ushort_t)(u >> 16);
}
__device__ __forceinline__ float bf2f(ushort_t h) {
  return __uint_as_float(((uint32_t)h) << 16);
}

__device__ __forceinline__ void async16(ushort_t* lds, const ushort_t* g) {
  __builtin_amdgcn_global_load_lds(
      (const __attribute__((address_space(1))) void*)g,
      (__attribute__((address_space(3))) void*)lds, 16, 0, 0);
}

// ---------------------------------------------------------------------------
// weight pack to bf16 [oc][k], k = dl*IC + ic; src[oc*K + ic*KD + dl]
// ---------------------------------------------------------------------------
__global__ __launch_bounds__(256) void pack_bf16_kernel(
    const float* __restrict__ src, ushort_t* __restrict__ dst,
    int K, int KD, int icShift)
{
  const int oc = blockIdx.x;
  const int icMask = (1 << icShift) - 1;
  for (int k = threadIdx.x; k < K; k += 256) {
    int ic = k & icMask, dl = k >> icShift;
    dst[(size_t)oc * K + k] = f2bf(src[(size_t)oc * K + ic * KD + dl]);
  }
}

// ---------------------------------------------------------------------------
// Generic bf16 MFMA GEMM, 128x128 tile, BK=32, global_load_lds staging.
// ---------------------------------------------------------------------------
template<int EPI>
__global__ __launch_bounds__(256, 2) void mfma_gemm(
    const ushort_t* __restrict__ Ab, const ushort_t* __restrict__ Bb,
    int K, int BS, int P, int NOUT,
    const float* __restrict__ bias, const float* __restrict__ res,
    float* __restrict__ outf, ushort_t* __restrict__ outh)
{
  __shared__ ushort_t As[128 * 32];
  __shared__ ushort_t Bs[128 * 32];
  const int t = threadIdx.x;
  const int w = t >> 6, l = t & 63;
  const int m0 = blockIdx.x * 128, n0 = blockIdx.y * 128;

  const int sub = l >> 2;
  const int kc8 = (l & 3) * 8;
  const ushort_t* aptr[2];
  const ushort_t* bptr[2];
  #pragma unroll
  for (int c = 0; c < 2; ++c) {
    int arow = m0 + w * 32 + c * 16 + sub;
    aptr[c] = Ab + (size_t)(arow >> 10) * BS + (size_t)(arow & 1023) * P + kc8;
    int brow = n0 + w * 32 + c * 16 + sub;
    bptr[c] = Bb + (size_t)brow * K + kc8;
  }

  const int wm = w >> 1, wn = w & 1;
  const int lm = l & 15, q = l >> 4;
  floatx4 acc[4][4];
  #pragma unroll
  for (int i = 0; i < 4; ++i)
    #pragma unroll
    for (int j = 0; j < 4; ++j)
      acc[i][j] = (floatx4){0.f, 0.f, 0.f, 0.f};

  const int kIters = K >> 5;
  for (int kt = 0; kt < kIters; ++kt) {
    __syncthreads();
    async16(&As[w * 1024 +   0], aptr[0]);
    async16(&As[w * 1024 + 512], aptr[1]);
    async16(&Bs[w * 1024 +   0], bptr[0]);
    async16(&Bs[w * 1024 + 512], bptr[1]);
    aptr[0] += 32; aptr[1] += 32; bptr[0] += 32; bptr[1] += 32;
    __syncthreads();
    short8 af[4], bf[4];
    #pragma unroll
    for (int i = 0; i < 4; ++i)
      af[i] = *(const short8*)&As[(wm * 64 + i * 16 + lm) * 32 + q * 8];
    #pragma unroll
    for (int i = 0; i < 4; ++i)
      bf[i] = *(const short8*)&Bs[(wn * 64 + i * 16 + lm) * 32 + q * 8];
    #pragma unroll
    for (int i = 0; i < 4; ++i)
      #pragma unroll
      for (int j = 0; j < 4; ++j)
        acc[i][j] = __builtin_amdgcn_mfma_f32_16x16x32_bf16(af[i], bf[j], acc[i][j], 0, 0, 0);
  }

  #pragma unroll
  for (int i = 0; i < 4; ++i) {
    #pragma unroll
    for (int j = 0; j < 4; ++j) {
      const int mbase = m0 + wm * 64 + i * 16 + q * 4;
      const int n = n0 + wn * 64 + j * 16 + lm;
      #pragma unroll
      for (int r = 0; r < 4; ++r) {
        const int m = mbase + r;
        float v = acc[i][j][r];
        if (EPI == 0) {
          outh[(size_t)m * NOUT + n] = f2bf(v);
        } else if (EPI == 1) {
          outf[(size_t)m * NOUT + n] = v + bias[n];
        } else {
          outf[(size_t)m * NOUT + n] = v + bias[n] + res[(size_t)m * NOUT + n];
        }
      }
    }
  }
}

// ---------------------------------------------------------------------------
// QKV projection via MFMA. grid (128, 3): blockIdx.x = 64-token tile,
// blockIdx.y = matrix (0=Q,1=K,2=V). W (64x64) staged to LDS in fragment
// order; A-fragments read from global fp32, converted in-register.
// Per head h: q[t, h*64+d] = sum_e x[t, h*64+e] * W[d][e].
// ---------------------------------------------------------------------------
__global__ __launch_bounds__(256) void qkv_mfma(
    const float* __restrict__ x,
    const float* __restrict__ Wq, const float* __restrict__ Wk, const float* __restrict__ Wv,
    ushort_t* __restrict__ qo, ushort_t* __restrict__ ko, ushort_t* __restrict__ vo)
{
  __shared__ ushort_t Ws[8 * 512];   // frag (nt,s): [((nt*2+s)*64 + lane)*8 + j]
  const int mat = blockIdx.y;
  const float* __restrict__ W = (mat == 0) ? Wq : (mat == 1) ? Wk : Wv;
  const int t = threadIdx.x;

  // stage W: element (oc, ic) -> frag slot (nt=oc>>4, s=ic>>5), lane quad*16+lm
  for (int e = t; e < 4096; e += 256) {
    const int oc = e >> 6, ic = e & 63;
    const int nt = oc >> 4, lmm = oc & 15, s = ic >> 5, qd = (ic >> 3) & 3, j = ic & 7;
    Ws[(((nt * 2 + s) * 4 + qd) * 16 + lmm) * 8 + j] = f2bf(W[e]);
  }

  const int w = t >> 6, l = t & 63;
  const int lm = l & 15, quad = l >> 4;
  const int tok0 = blockIdx.x * 64 + w * 16;

  // A-fragments: token row = tok0+lm, k = h*64 + s*32 + quad*8 .. +8
  short8 af[16];
  {
    const float* xrow = x + (size_t)(tok0 + lm) * CH + quad * 8;
    #pragma unroll
    for (int h = 0; h < 8; ++h) {
      #pragma unroll
      for (int s = 0; s < 2; ++s) {
        const float4 a = *(const float4*)(xrow + h * 64 + s * 32);
        const float4 b = *(const float4*)(xrow + h * 64 + s * 32 + 4);
        short8 f;
        f[0] = (short)f2bf(a.x); f[1] = (short)f2bf(a.y);
        f[2] = (short)f2bf(a.z); f[3] = (short)f2bf(a.w);
        f[4] = (short)f2bf(b.x); f[5] = (short)f2bf(b.y);
        f[6] = (short)f2bf(b.z); f[7] = (short)f2bf(b.w);
        af[h * 2 + s] = f;
      }
    }
  }
  __syncthreads();

  short8 bfr[8];
  #pragma unroll
  for (int nt = 0; nt < 4; ++nt)
    #pragma unroll
    for (int s = 0; s < 2; ++s)
      bfr[nt * 2 + s] = *(const short8*)&Ws[((nt * 2 + s) * 64 + l) * 8];

  const int n = tok0 >> 10, lpos = tok0 & 1023;
  ushort_t* outp;
  size_t base;
  if (mat == 0) { base = ((size_t)n * LQ + lpos) * CH; outp = qo; }
  else          { base = ((size_t)n * LP + lpos) * CH; outp = (mat == 1) ? ko : vo; }

  #pragma unroll
  for (int h = 0; h < 8; ++h) {
    floatx4 acc[4];
    #pragma unroll
    for (int nt = 0; nt < 4; ++nt) acc[nt] = (floatx4){0.f, 0.f, 0.f, 0.f};
    #pragma unroll
    for (int nt = 0; nt < 4; ++nt)
      #pragma unroll
      for (int s = 0; s < 2; ++s)
        acc[nt] = __builtin_amdgcn_mfma_f32_16x16x32_bf16(
            af[h * 2 + s], bfr[nt * 2 + s], acc[nt], 0, 0, 0);
    // C/D: col = lane&15 (d within tile), row = quad*4 + r (token)
    #pragma unroll
    for (int nt = 0; nt < 4; ++nt)
      #pragma unroll
      for (int r = 0; r < 4; ++r)
        outp[base + (size_t)(quad * 4 + r) * CH + h * 64 + nt * 16 + lm] =
            f2bf(acc[nt][r]);
  }
}

__global__ __launch_bounds__(256) void persist_kernel(
    const float* __restrict__ pk, const float* __restrict__ pv,
    ushort_t* __restrict__ ko, ushort_t* __restrict__ vo)
{
  const int t = blockIdx.x * 256 + threadIdx.x;
  const int n = t >> 13, p = (t >> 9) & 15, c = t & 511, d = c & 63;
  const size_t o = ((size_t)n * LP + LQ + p) * CH + c;
  ko[o] = f2bf(pk[p * 64 + d]);
  vo[o] = f2bf(pv[p * 64 + d]);
}

// ---------------------------------------------------------------------------
// V transpose: Vb [n][k(1040)][512] -> VT [n][d(512)][1040]
// ---------------------------------------------------------------------------
__global__ __launch_bounds__(256) void vtrans_kernel(
    const ushort_t* __restrict__ Vb, ushort_t* __restrict__ VT)
{
  __shared__ ushort_t Ls[16 * 520];
  const int n = blockIdx.y, k0 = blockIdx.x * 16;
  const int t = threadIdx.x;
  const int r = t >> 4;
  {
    const ushort_t* src = Vb + ((size_t)(n * LP + k0 + r)) * 512 + (t & 15) * 8;
    ushort_t* dst = &Ls[r * 520 + (t & 15) * 8];
    #pragma unroll
    for (int it = 0; it < 4; ++it)
      *(short8*)(dst + it * 128) = *(const short8*)(src + it * 128);
  }
  __syncthreads();
  #pragma unroll
  for (int rep = 0; rep < 2; ++rep) {
    const int d = t + rep * 256;
    short8 v0, v1;
    #pragma unroll
    for (int j = 0; j < 8; ++j) {
      v0[j] = (short)Ls[j * 520 + d];
      v1[j] = (short)Ls[(8 + j) * 520 + d];
    }
    ushort_t* dst = VT + ((size_t)(n * 512 + d)) * LP + k0;
    *(short8*)(dst)     = v0;
    *(short8*)(dst + 8) = v1;
  }
}

// ---------------------------------------------------------------------------
// MFMA flash attention with talking heads + ALiBi.
// ---------------------------------------------------------------------------
__global__ __launch_bounds__(256, 2) void attn_mfma(
    const ushort_t* __restrict__ Qb, const ushort_t* __restrict__ Kb,
    const ushort_t* __restrict__ VT,
    const float* __restrict__ thpre, const float* __restrict__ thpost,
    ushort_t* __restrict__ aob)
{
  __shared__ ushort_t Ks[16 * 520];     // K tile [key][d], row pad 8
  __shared__ ushort_t Vt[512 * 40];     // V^T tile [d][k-pair 32], row pad 8
  __shared__ float   Ps[8 * 16 * 36];   // P [g][q][k-pair 32], row pad 4
  const int n = blockIdx.y, q0 = blockIdx.x * 16;
  const int t = threadIdx.x;
  const int w = t >> 6, l = t & 63;
  const int lm = l & 15, quad = l >> 4;
  const float invs = 0.044194173824159216f;  // 1/sqrt(512)

  short8 qf[16];
  {
    const ushort_t* qrow = Qb + ((size_t)(n * LQ + q0 + lm)) * 512 + quad * 8;
    #pragma unroll
    for (int h = 0; h < 8; ++h) {
      qf[h * 2 + 0] = *(const short8*)(qrow + h * 64);
      qf[h * 2 + 1] = *(const short8*)(qrow + h * 64 + 32);
    }
  }
  float tps[2][8], psl[2], tpo[2][8];
  #pragma unroll
  for (int gg = 0; gg < 2; ++gg) {
    const int g = w * 2 + gg;
    float ps = 0.f;
    #pragma unroll
    for (int h = 0; h < 8; ++h) {
      float tv = thpre[g * 8 + h] * invs;
      tps[gg][h] = tv;
      ps += tv * (1.0f / (float)(2 << h));   // slope_h = 2^-(h+1)
      tpo[gg][h] = thpost[g * 8 + h];
    }
    psl[gg] = ps;
  }

  float m_[2][4], z_[2][4];
  #pragma unroll
  for (int gg = 0; gg < 2; ++gg)
    #pragma unroll
    for (int r = 0; r < 4; ++r) { m_[gg][r] = -1e30f; z_[gg][r] = 0.f; }

  // ---------------- pass 1: stats ----------------
  for (int step = 0; step < 65; ++step) {
    const int k0 = step * 16;
    {
      const ushort_t* src = Kb + ((size_t)(n * LP + k0 + (t >> 4))) * 512 + (t & 15) * 8;
      ushort_t* dst = &Ks[(t >> 4) * 520 + (t & 15) * 8];
      #pragma unroll
      for (int it = 0; it < 4; ++it)
        *(short8*)(dst + it * 128) = *(const short8*)(src + it * 128);
    }
    __syncthreads();
    floatx4 ef[8];
    {
      const ushort_t* kbase = &Ks[lm * 520 + quad * 8];
      #pragma unroll
      for (int h = 0; h < 8; ++h) {
        floatx4 e = (floatx4){0.f, 0.f, 0.f, 0.f};
        short8 b0 = *(const short8*)(kbase + h * 64);
        short8 b1 = *(const short8*)(kbase + h * 64 + 32);
        e = __builtin_amdgcn_mfma_f32_16x16x32_bf16(qf[h * 2 + 0], b0, e, 0, 0, 0);
        e = __builtin_amdgcn_mfma_f32_16x16x32_bf16(qf[h * 2 + 1], b1, e, 0, 0, 0);
        ef[h] = e;
      }
    }
    const bool alibi = (step < 64);
    #pragma unroll
    for (int r = 0; r < 4; ++r) {
      const float dist = fabsf((float)(q0 + quad * 4 + r - (k0 + lm)));
      #pragma unroll
      for (int gg = 0; gg < 2; ++gg) {
        float s = tps[gg][0] * ef[0][r];
        #pragma unroll
        for (int h = 1; h < 8; ++h) s += tps[gg][h] * ef[h][r];
        if (alibi) s -= dist * psl[gg];
        const float mo = m_[gg][r];
        const float mn = fmaxf(mo, s);
        z_[gg][r] = z_[gg][r] * __expf(mo - mn) + __expf(s - mn);
        m_[gg][r] = mn;
      }
    }
    __syncthreads();
  }
  #pragma unroll
  for (int off = 1; off < 16; off <<= 1) {
    #pragma unroll
    for (int gg = 0; gg < 2; ++gg)
      #pragma unroll
      for (int r = 0; r < 4; ++r) {
        const float mo = __shfl_xor(m_[gg][r], off);
        const float zo = __shfl_xor(z_[gg][r], off);
        const float mn = fmaxf(m_[gg][r], mo);
        z_[gg][r] = z_[gg][r] * __expf(m_[gg][r] - mn) + zo * __expf(mo - mn);
        m_[gg][r] = mn;
      }
  }
  float zi[2][4];
  #pragma unroll
  for (int gg = 0; gg < 2; ++gg)
    #pragma unroll
    for (int r = 0; r < 4; ++r) zi[gg][r] = 1.0f / z_[gg][r];

  // ---------------- pass 2: P + AV ----------------
  floatx4 o_[2][4];
  #pragma unroll
  for (int gg = 0; gg < 2; ++gg)
    #pragma unroll
    for (int ch = 0; ch < 4; ++ch) o_[gg][ch] = (floatx4){0.f, 0.f, 0.f, 0.f};

  for (int pair = 0; pair < 33; ++pair) {
    const int nsub = (pair == 32) ? 1 : 2;
    for (int sub = 0; sub < nsub; ++sub) {
      const int step = pair * 2 + sub, k0 = step * 16;
      {
        const ushort_t* src = Kb + ((size_t)(n * LP + k0 + (t >> 4))) * 512 + (t & 15) * 8;
        ushort_t* dst = &Ks[(t >> 4) * 520 + (t & 15) * 8];
        #pragma unroll
        for (int it = 0; it < 4; ++it)
          *(short8*)(dst + it * 128) = *(const short8*)(src + it * 128);
      }
      #pragma unroll
      for (int rep = 0; rep < 2; ++rep) {
        const int d = t + rep * 256;
        const ushort_t* src = VT + ((size_t)(n * 512 + d)) * LP + k0;
        ushort_t* dst = &Vt[d * 40 + sub * 16];
        *(short8*)(dst)     = *(const short8*)(src);
        *(short8*)(dst + 8) = *(const short8*)(src + 8);
      }
      __syncthreads();
      floatx4 ef[8];
      {
        const ushort_t* kbase = &Ks[lm * 520 + quad * 8];
        #pragma unroll
        for (int h = 0; h < 8; ++h) {
          floatx4 e = (floatx4){0.f, 0.f, 0.f, 0.f};
          short8 b0 = *(const short8*)(kbase + h * 64);
          short8 b1 = *(const short8*)(kbase + h * 64 + 32);
          e = __builtin_amdgcn_mfma_f32_16x16x32_bf16(qf[h * 2 + 0], b0, e, 0, 0, 0);
          e = __builtin_amdgcn_mfma_f32_16x16x32_bf16(qf[h * 2 + 1], b1, e, 0, 0, 0);
          ef[h] = e;
        }
      }
      const bool alibi = (step < 64);
      #pragma unroll
      for (int r = 0; r < 4; ++r) {
        const float dist = fabsf((float)(q0 + quad * 4 + r - (k0 + lm)));
        #pragma unroll
        for (int gg = 0; gg < 2; ++gg) {
          float s = tps[gg][0] * ef[0][r];
          #pragma unroll
          for (int h = 1; h < 8; ++h) s += tps[gg][h] * ef[h][r];
          if (alibi) s -= dist * psl[gg];
          const float p = __expf(s - m_[gg][r]) * zi[gg][r];
          Ps[((w * 2 + gg) * 16 + quad * 4 + r) * 36 + sub * 16 + lm] = p;
          if (pair == 32)
            Ps[((w * 2 + gg) * 16 + quad * 4 + r) * 36 + 16 + lm] = 0.f;
        }
      }
      __syncthreads();
    }
    float pm[2][8];
    #pragma unroll
    for (int gg = 0; gg < 2; ++gg)
      #pragma unroll
      for (int j = 0; j < 8; ++j) pm[gg][j] = 0.f;
    #pragma unroll
    for (int g = 0; g < 8; ++g) {
      const float4 pa = *(const float4*)&Ps[(g * 16 + lm) * 36 + quad * 8];
      const float4 pb = *(const float4*)&Ps[(g * 16 + lm) * 36 + quad * 8 + 4];
      #pragma unroll
      for (int gg = 0; gg < 2; ++gg) {
        const float tw = tpo[gg][g];
        pm[gg][0] += tw * pa.x; pm[gg][1] += tw * pa.y;
        pm[gg][2] += tw * pa.z; pm[gg][3] += tw * pa.w;
        pm[gg][4] += tw * pb.x; pm[gg][5] += tw * pb.y;
        pm[gg][6] += tw * pb.z; pm[gg][7] += tw * pb.w;
      }
    }
    short8 pk[2];
    #pragma unroll
    for (int gg = 0; gg < 2; ++gg)
      #pragma unroll
      for (int j = 0; j < 8; ++j) pk[gg][j] = (short)f2bf(pm[gg][j]);
    #pragma unroll
    for (int gg = 0; gg < 2; ++gg) {
      #pragma unroll
      for (int ch = 0; ch < 4; ++ch) {
        const int d = (w * 2 + gg) * 64 + ch * 16 + lm;
        const short8 vf = *(const short8*)&Vt[d * 40 + quad * 8];
        o_[gg][ch] = __builtin_amdgcn_mfma_f32_16x16x32_bf16(pk[gg], vf, o_[gg][ch], 0, 0, 0);
      }
    }
    __syncthreads();
  }

  #pragma unroll
  for (int gg = 0; gg < 2; ++gg)
    #pragma unroll
    for (int ch = 0; ch < 4; ++ch) {
      const int d = (w * 2 + gg) * 64 + ch * 16 + lm;
      #pragma unroll
      for (int r = 0; r < 4; ++r)
        aob[((size_t)(n * LQ + q0 + quad * 4 + r)) * 512 + d] = f2bf(o_[gg][ch][r]);
    }
}

// ---------------------------------------------------------------------------
// swiglu: h = silu(h1+b1)*(h2+b2), raw [8192][4096] bf16 -> padded bf16
// ---------------------------------------------------------------------------
__global__ __launch_bounds__(256) void swiglu_kernel(
    const ushort_t* __restrict__ hraw, const float* __restrict__ bias,
    ushort_t* __restrict__ hpad)
{
  const int tok = blockIdx.x;
  const int n = tok >> 10, l = tok & 1023;
  const size_t src = (size_t)tok * 4096;
  const size_t dst = ((size_t)n * 1026 + l + 1) * 2048;
  for (int c = threadIdx.x; c < 2048; c += 256) {
    float h1 = bf2f(hraw[src + c]) + bias[c];
    float h2 = bf2f(hraw[src + 2048 + c]) + bias[2048 + c];
    float s = h1 / (1.f + __expf(-h1));
    hpad[dst + c] = f2bf(s * h2);
  }
}

__global__ __launch_bounds__(256) void zero_pads_kernel(
    ushort_t* __restrict__ x1b, ushort_t* __restrict__ hpad)
{
  const int b = blockIdx.x;
  const int n = b >> 1, side = b & 1;
  const size_t r = (size_t)n * 1026 + side * 1025;
  ushort2 z; z.x = 0; z.y = 0;
  *(ushort2*)&x1b[r * 512 + threadIdx.x * 2] = z;
  #pragma unroll
  for (int i = 0; i < 4; ++i)
    *(ushort2*)&hpad[r * 2048 + (threadIdx.x + 256 * i) * 2] = z;
}

// ---------------------------------------------------------------------------
// LayerNorm (fp32) + optional bf16 padded copy
// ---------------------------------------------------------------------------
__global__ __launch_bounds__(256) void ln_kernel(
    const float* __restrict__ in, const float* __restrict__ res,
    const float* __restrict__ g, const float* __restrict__ b,
    float* __restrict__ outp, ushort_t* __restrict__ bfout)
{
  const int w = threadIdx.x >> 6, lane = threadIdx.x & 63;
  const int tok = blockIdx.x * 4 + w;
  const size_t base = (size_t)tok * CH;
  float4 v0 = *(const float4*)&in[base + (lane << 2)];
  float4 v1 = *(const float4*)&in[base + 256 + (lane << 2)];
  if (res != nullptr) {
    float4 r0 = *(const float4*)&res[base + (lane << 2)];
    float4 r1 = *(const float4*)&res[base + 256 + (lane << 2)];
    v0.x += r0.x; v0.y += r0.y; v0.z += r0.z; v0.w += r0.w;
    v1.x += r1.x; v1.y += r1.y; v1.z += r1.z; v1.w += r1.w;
  }
  float s = v0.x + v0.y + v0.z + v0.w + v1.x + v1.y + v1.z + v1.w;
  #pragma unroll
  for (int off = 32; off > 0; off >>= 1) s += __shfl_xor(s, off);
  const float mu = s * (1.f / 512.f);
  float d0 = v0.x - mu, d1 = v0.y - mu, d2 = v0.z - mu, d3 = v0.w - mu;
  float d4 = v1.x - mu, d5 = v1.y - mu, d6 = v1.z - mu, d7 = v1.w - mu;
  float vs = d0*d0 + d1*d1 + d2*d2 + d3*d3 + d4*d4 + d5*d5 + d6*d6 + d7*d7;
  #pragma unroll
  for (int off = 32; off > 0; off >>= 1) vs += __shfl_xor(vs, off);
  const float r = rsqrtf(vs * (1.f / 512.f) + 1e-5f);
  float4 ga = *(const float4*)&g[(lane << 2)];
  float4 gb = *(const float4*)&g[256 + (lane << 2)];
  float4 ba = *(const float4*)&b[(lane << 2)];
  float4 bb = *(const float4*)&b[256 + (lane << 2)];
  float4 o0, o1;
  o0.x = d0 * r * ga.x + ba.x; o0.y = d1 * r * ga.y + ba.y;
  o0.z = d2 * r * ga.z + ba.z; o0.w = d3 * r * ga.w + ba.w;
  o1.x = d4 * r * gb.x + bb.x; o1.y = d5 * r * gb.y + bb.y;
  o1.z = d6 * r * gb.z + bb.z; o1.w = d7 * r * gb.w + bb.w;
  *(float4*)&outp[base + (lane << 2)] = o0;
  *(float4*)&outp[base + 256 + (lane << 2)] = o1;
  if (bfout != nullptr) {
    const int n = tok >> 10, ll = tok & 1023;
    const size_t bb2 = ((size_t)n * 1026 + ll + 1) * 512;
    ushort4 u0 = make_ushort4(f2bf(o0.x), f2bf(o0.y), f2bf(o0.z), f2bf(o0.w));
    ushort4 u1 = make_ushort4(f2bf(o1.x), f2bf(o1.y), f2bf(o1.z), f2bf(o1.w));
    *(ushort4*)&bfout[bb2 + (lane << 2)] = u0;
    *(ushort4*)&bfout[bb2 + 256 + (lane << 2)] = u1;
  }
}

// ---------------------------------------------------------------------------
extern "C" void kernel_launch(void* const* d_in, const int* in_sizes, int n_in,
                              void* d_out, int out_size, void* d_ws, size_t ws_size,
                              hipStream_t stream)
{
  (void)in_sizes; (void)n_in; (void)out_size; (void)ws_size;
  const float* x      = (const float*)d_in[0];
  const float* Wq     = (const float*)d_in[1];
  const float* Wk     = (const float*)d_in[2];
  const float* Wv     = (const float*)d_in[3];
  const float* Wo     = (const float*)d_in[4];
  const float* bo     = (const float*)d_in[5];
  const float* th_pre = (const float*)d_in[6];
  const float* th_post= (const float*)d_in[7];
  const float* p_keys = (const float*)d_in[8];
  const float* p_vals = (const float*)d_in[9];
  const float* c1w    = (const float*)d_in[10];
  const float* c1b    = (const float*)d_in[11];
  const float* c2w    = (const float*)d_in[12];
  const float* c2b    = (const float*)d_in[13];
  const float* ln1g   = (const float*)d_in[14];
  const float* ln1b   = (const float*)d_in[15];
  const float* ln2g   = (const float*)d_in[16];
  const float* ln2b   = (const float*)d_in[17];

  float* ws  = (float*)d_ws;
  float* out = (float*)d_out;

  ushort_t* Qb   = (ushort_t*)(ws + O_QB);
  ushort_t* Kb   = (ushort_t*)(ws + O_KB);
  ushort_t* Vb   = (ushort_t*)(ws + O_VB);
  ushort_t* VT   = (ushort_t*)(ws + O_VT);
  ushort_t* aob  = (ushort_t*)(ws + O_AOB);
  float*    abf  = ws + O_AF;
  float*    fbf  = abf;
  ushort_t* x1b  = (ushort_t*)(ws + O_X1B);
  ushort_t* hpad = (ushort_t*)(ws + O_HPAD);
  ushort_t* hraw = (ushort_t*)ws;         // overlays dead attn buffers
  ushort_t* w1p  = (ushort_t*)(ws + O_W1);
  ushort_t* w2p  = (ushort_t*)(ws + O_W2);
  ushort_t* wop  = (ushort_t*)(ws + O_WO);

  pack_bf16_kernel<<<4096, 256, 0, stream>>>(c1w, w1p, 1536, 3, 9);
  pack_bf16_kernel<<<512,  256, 0, stream>>>(c2w, w2p, 6144, 3, 11);
  pack_bf16_kernel<<<512,  256, 0, stream>>>(Wo,  wop, 512,  1, 9);

  qkv_mfma<<<dim3(128, 3), 256, 0, stream>>>(x, Wq, Wk, Wv, Qb, Kb, Vb);
  persist_kernel<<<256, 256, 0, stream>>>(p_keys, p_vals, Kb, Vb);
  vtrans_kernel<<<dim3(65, 8), 256, 0, stream>>>(Vb, VT);

  attn_mfma<<<dim3(64, 8), 256, 0, stream>>>(Qb, Kb, VT, th_pre, th_post, aob);

  // Wo: M=8192 N=512 K=512, +bias +residual(x) -> abf fp32
  mfma_gemm<2><<<dim3(64, 4), 256, 0, stream>>>(
      aob, wop, 512, 1024 * 512, 512, 512, bo, x, abf, nullptr);

  ln_kernel<<<2048, 256, 0, stream>>>(abf, nullptr, ln1g, ln1b, out, x1b);
  zero_pads_kernel<<<16, 256, 0, stream>>>(x1b, hpad);

  // conv1: M=8192 N=4096 K=1536 -> hraw bf16
  mfma_gemm<0><<<dim3(64, 32), 256, 0, stream>>>(
      x1b, w1p, 1536, 1026 * 512, 512, 4096, nullptr, nullptr, nullptr, hraw);

  swiglu_kernel<<<8192, 256, 0, stream>>>(hraw, c1b, hpad);

  // conv2: M=8192 N=512 K=6144, +bias -> fbf fp32
  mfma_gemm<1><<<dim3(64, 4), 256, 0, stream>>>(
      hpad, w2p, 6144, 1026 * 2048, 2048, 512, c2b, nullptr, fbf, nullptr);

  ln_kernel<<<2048, 256, 0, stream>>>(fbf, out, ln2g, ln2b, out, nullptr);
}